// Round 6
// baseline (380.322 us; speedup 1.0000x reference)
//
#include <hip/hip_runtime.h>

#define NB 4
#define NP 16384
#define DD 512
#define HH 256
#define CC 2
#define KSEL 11468
#define TOTP (NB*NP)
#define BCAP 4096

// d_out offsets (floats)
#define OFF_COMB (NB*KSEL*DD)            // 23486464
#define OFF_IDX  (OFF_COMB + NB*NP)      // 23552000
#define OFF_LOSS (OFF_IDX + NB*KSEL)     // 23597872

// ws offsets (floats)
#define WS_ALOGIT 0
#define WS_SELIDX (2*NB*CC*NP)               // 262144 (ints)
#define WS_MZ     (WS_SELIDX + NB*KSEL)      // (16 floats)
#define WS_BCNT   (WS_MZ + 16)               // ints (4)
#define WS_BLIST  (WS_BCNT + 4)              // ints (4*BCAP)
#define WS_TOP16  (WS_BLIST + NB*BCAP)       // ints (8*16)
#define WS_CE     (WS_TOP16 + 128)           // floats (128)

typedef __attribute__((ext_vector_type(8))) short short8x;
typedef __attribute__((ext_vector_type(4))) float f32x4;

__device__ __forceinline__ unsigned short f2bf(float x){
  unsigned u = __float_as_uint(x);
  unsigned r = (u + 0x7FFFu + ((u >> 16) & 1u)) >> 16;
  return (unsigned short)r;
}

// ---------------------------------------------------------------------------
// Wa (512x256 f32) -> Wa_t (256x512 bf16), transposed, stored at d_out head.
// ---------------------------------------------------------------------------
__global__ __launch_bounds__(256) void waconv_kernel(
    const float* __restrict__ Wa, unsigned short* __restrict__ WaT)
{
  __shared__ float tile[32][33];
  const int tx = threadIdx.x, ty = threadIdx.y;   // 32 x 8
  const int k0 = blockIdx.x * 32, n0 = blockIdx.y * 32;
  #pragma unroll
  for (int i=0;i<4;++i)
    tile[ty+8*i][tx] = Wa[(size_t)(k0+ty+8*i)*HH + n0 + tx];
  __syncthreads();
  #pragma unroll
  for (int i=0;i<4;++i)
    WaT[(size_t)(n0+ty+8*i)*DD + k0 + tx] = f2bf(tile[tx][ty+8*i]);
}

// ---------------------------------------------------------------------------
// MFMA GEMM: a_logits[b,c,n] = Wbr[c].relu(f[n]@Wa+ba) + bbr[c], bf16 inputs.
// BM=128, BN=256(full H), BK=64; 8 waves (2M x 4N), wave tile 64x64.
// (unchanged — proven)
// ---------------------------------------------------------------------------
__global__ __launch_bounds__(512) void gemm_mfma_kernel(
    const float* __restrict__ feat, const unsigned short* __restrict__ WaT,
    const float* __restrict__ ba, const float* __restrict__ Wbr,
    const float* __restrict__ bbr, float* __restrict__ aL)
{
  __shared__ __attribute__((aligned(16))) unsigned char smem[65536];
  __shared__ float sBA[HH], sW0[HH], sW1[HH];
  unsigned char* sA = smem;                 // 128*64 bf16 = 16 KB (swizzled)
  unsigned char* sB = smem + 16384;         // 256*64 bf16 = 32 KB (swizzled)

  const int tid  = threadIdx.x;
  const int lane = tid & 63;
  const int wid  = tid >> 6;
  const int wm = wid >> 2, wn = wid & 3;
  const int fr = lane & 15, fq = lane >> 4;
  const int p0 = blockIdx.x * 128;
  const float bb0 = bbr[0], bb1 = bbr[1];

  if (tid < HH){ sBA[tid] = ba[tid]; sW0[tid] = Wbr[tid]; sW1[tid] = Wbr[HH+tid]; }

  f32x4 acc[4][4];
  #pragma unroll
  for (int i=0;i<4;++i)
    #pragma unroll
    for (int j=0;j<4;++j)
      acc[i][j] = (f32x4){0.f,0.f,0.f,0.f};

  const int am = tid >> 2, akq = (tid & 3) * 16;     // A staging: row, k-offset
  const int bn = tid >> 1, bhf = tid & 1;            // B staging

  for (int k0 = 0; k0 < DD; k0 += 64){
    __syncthreads();
    // ---- stage A: 128x64 fp32 -> bf16, swizzled K-major
    {
      const float4* src = reinterpret_cast<const float4*>(
          feat + (size_t)(p0 + am)*DD + k0 + akq);
      float4 v0 = src[0], v1 = src[1], v2 = src[2], v3 = src[3];
      unsigned short u[16];
      u[0]=f2bf(v0.x); u[1]=f2bf(v0.y); u[2]=f2bf(v0.z); u[3]=f2bf(v0.w);
      u[4]=f2bf(v1.x); u[5]=f2bf(v1.y); u[6]=f2bf(v1.z); u[7]=f2bf(v1.w);
      u[8]=f2bf(v2.x); u[9]=f2bf(v2.y); u[10]=f2bf(v2.z); u[11]=f2bf(v2.w);
      u[12]=f2bf(v3.x); u[13]=f2bf(v3.y); u[14]=f2bf(v3.z); u[15]=f2bf(v3.w);
      uint4 w0, w1;
      w0.x = (unsigned)u[0] | ((unsigned)u[1]<<16);
      w0.y = (unsigned)u[2] | ((unsigned)u[3]<<16);
      w0.z = (unsigned)u[4] | ((unsigned)u[5]<<16);
      w0.w = (unsigned)u[6] | ((unsigned)u[7]<<16);
      w1.x = (unsigned)u[8] | ((unsigned)u[9]<<16);
      w1.y = (unsigned)u[10] | ((unsigned)u[11]<<16);
      w1.z = (unsigned)u[12] | ((unsigned)u[13]<<16);
      w1.w = (unsigned)u[14] | ((unsigned)u[15]<<16);
      const int swz = (am & 7) << 4;
      *reinterpret_cast<uint4*>(sA + (((am*128) + akq*2) ^ swz)) = w0;
      *reinterpret_cast<uint4*>(sA + (((am*128) + akq*2 + 16) ^ swz)) = w1;
    }
    // ---- stage B: 256x64 bf16 from WaT, swizzled K-major
    {
      const uint4* src = reinterpret_cast<const uint4*>(
          WaT + (size_t)bn*DD + k0 + bhf*32);
      uint4 q0 = src[0], q1 = src[1], q2 = src[2], q3 = src[3];
      const int swz = (bn & 7) << 4;
      const int base = bn*128 + bhf*64;
      *reinterpret_cast<uint4*>(sB + ((base     ) ^ swz)) = q0;
      *reinterpret_cast<uint4*>(sB + ((base + 16) ^ swz)) = q1;
      *reinterpret_cast<uint4*>(sB + ((base + 32) ^ swz)) = q2;
      *reinterpret_cast<uint4*>(sB + ((base + 48) ^ swz)) = q3;
    }
    __syncthreads();
    // ---- MFMA
    #pragma unroll
    for (int kf = 0; kf < 2; ++kf){
      short8x af[4], bf[4];
      #pragma unroll
      for (int mf = 0; mf < 4; ++mf){
        int m_loc = wm*64 + mf*16 + fr;
        int off = ((m_loc*128 + kf*64 + fq*16) ^ ((m_loc & 7) << 4));
        af[mf] = *reinterpret_cast<const short8x*>(sA + off);
      }
      #pragma unroll
      for (int nf = 0; nf < 4; ++nf){
        int n_loc = wn*64 + nf*16 + fr;
        int off = ((n_loc*128 + kf*64 + fq*16) ^ ((n_loc & 7) << 4));
        bf[nf] = *reinterpret_cast<const short8x*>(sB + off);
      }
      #pragma unroll
      for (int mf = 0; mf < 4; ++mf)
        #pragma unroll
        for (int nf = 0; nf < 4; ++nf)
          acc[mf][nf] = __builtin_amdgcn_mfma_f32_16x16x32_bf16(
              af[mf], bf[nf], acc[mf][nf], 0, 0, 0);
    }
  }
  __syncthreads();

  // ---- epilogue: relu + Wbr projection via LDS h-tile, M in halves of 64
  float* hS = reinterpret_cast<float*>(smem);
  #pragma unroll
  for (int mh = 0; mh < 2; ++mh){
    if (wm == mh){
      #pragma unroll
      for (int mf = 0; mf < 4; ++mf)
        #pragma unroll
        for (int nf = 0; nf < 4; ++nf)
          #pragma unroll
          for (int r = 0; r < 4; ++r){
            int row = mf*16 + fq*4 + r;
            int col = wn*64 + nf*16 + fr;
            hS[row*256 + col] = acc[mf][nf][r];
          }
    }
    __syncthreads();
    {
      const int row = tid >> 3, cg = tid & 7;
      float s0 = 0.f, s1 = 0.f;
      #pragma unroll
      for (int j = 0; j < 8; ++j){
        int col = cg*4 + j*32;
        float4 hv = *reinterpret_cast<const float4*>(&hS[row*256 + col]);
        float xs[4] = {hv.x, hv.y, hv.z, hv.w};
        #pragma unroll
        for (int u = 0; u < 4; ++u){
          int ccol = col + u;
          float x = fmaxf(xs[u] + sBA[ccol], 0.f);
          s0 += x * sW0[ccol];
          s1 += x * sW1[ccol];
        }
      }
      s0 += __shfl_xor(s0,1); s1 += __shfl_xor(s1,1);
      s0 += __shfl_xor(s0,2); s1 += __shfl_xor(s1,2);
      s0 += __shfl_xor(s0,4); s1 += __shfl_xor(s1,4);
      if (cg == 0){
        int p = p0 + mh*64 + row;
        int b = p >> 14, nl = p & (NP-1);
        aL[((size_t)b*CC + 0)*NP + nl] = s0 + bb0;
        aL[((size_t)b*CC + 1)*NP + nl] = s1 + bb1;
      }
    }
    __syncthreads();
  }
}

// ---------------------------------------------------------------------------
// Per-(b,c) row max + 1/Z (double accum). One block per row (8 blocks).
// (unchanged — proven)
// ---------------------------------------------------------------------------
__global__ __launch_bounds__(1024) void smstat_kernel(
    const float* __restrict__ aL, float* __restrict__ mz)
{
  __shared__ float  s_redf[16];
  __shared__ double s_redd[16];
  __shared__ float  s_max;
  const int tid = threadIdx.x;
  const int lane = tid & 63, wid = tid >> 6;
  const int r = blockIdx.x;                 // r = b*2 + c
  const float* a = aL + (size_t)r*NP;
  float m = -1e30f;
  for (int n=tid; n<NP; n+=1024) m = fmaxf(m, a[n]);
  #pragma unroll
  for (int off=1; off<64; off<<=1) m = fmaxf(m, __shfl_xor(m, off));
  if (lane==0) s_redf[wid]=m;
  __syncthreads();
  if (tid==0){ float mm=s_redf[0]; for(int w=1;w<16;++w) mm=fmaxf(mm,s_redf[w]); s_max=mm; }
  __syncthreads();
  m = s_max;
  double ls = 0.0;
  for (int n=tid;n<NP;n+=1024) ls += (double)expf(a[n]-m);
  #pragma unroll
  for (int off=1; off<64; off<<=1) ls += __shfl_xor(ls, off);
  if (lane==0) s_redd[wid]=ls;
  __syncthreads();
  if (tid==0){
    double t=0; for(int w=0;w<16;++w) t+=s_redd[w];
    mz[r*2+0]=m; mz[r*2+1]=(float)(1.0/t);
  }
}

// ---------------------------------------------------------------------------
// Fused: combined finalize + approx threshold radix + band list.
// Register-resident chunks; attn no longer materialized (top16 recomputes).
// ---------------------------------------------------------------------------
__global__ __launch_bounds__(1024) void selTF_kernel(
    const float* __restrict__ aL, const float* __restrict__ mz,
    float* __restrict__ comb, int* __restrict__ bcnt, int* __restrict__ blist)
{
  __shared__ unsigned s_red[2][16];
  __shared__ int s_cnt;
  const int tid = threadIdx.x;
  const int b = blockIdx.x;
  const int lane = tid & 63, wid = tid >> 6;
  const float m0 = mz[b*4+0], iz0 = mz[b*4+1], m1 = mz[b*4+2], iz1 = mz[b*4+3];
  const float* a0 = aL + ((size_t)b*CC + 0)*NP;
  const float* a1 = aL + ((size_t)b*CC + 1)*NP;
  float* oc = comb + (size_t)b*NP;
  const int n0 = tid*16;

  unsigned v[16];
  #pragma unroll
  for (int g=0; g<4; ++g){
    float4 qa = *reinterpret_cast<const float4*>(a0 + n0 + g*4);
    float4 qb = *reinterpret_cast<const float4*>(a1 + n0 + g*4);
    float4 CV;
    CV.x = 0.5f*(expf(qa.x-m0)*iz0 + expf(qb.x-m1)*iz1);
    CV.y = 0.5f*(expf(qa.y-m0)*iz0 + expf(qb.y-m1)*iz1);
    CV.z = 0.5f*(expf(qa.z-m0)*iz0 + expf(qb.z-m1)*iz1);
    CV.w = 0.5f*(expf(qa.w-m0)*iz0 + expf(qb.w-m1)*iz1);
    *reinterpret_cast<float4*>(oc + n0 + g*4) = CV;
    v[g*4+0]=__float_as_uint(CV.x);
    v[g*4+1]=__float_as_uint(CV.y);
    v[g*4+2]=__float_as_uint(CV.z);
    v[g*4+3]=__float_as_uint(CV.w);
  }
  if (tid==0) s_cnt = 0;

  unsigned cur = 0;
  #pragma unroll 1
  for (int bit=31; bit>=12; --bit){
    unsigned trial = cur | (1u<<bit);
    int c = 0;
    #pragma unroll
    for (int i=0;i<16;++i) c += (v[i] >= trial) ? 1 : 0;
    #pragma unroll
    for (int off=1; off<64; off<<=1) c += __shfl_xor(c, off);
    if (lane==0) s_red[bit&1][wid] = (unsigned)c;
    __syncthreads();
    unsigned tot=0;
    #pragma unroll
    for (int w=0;w<16;++w) tot += s_red[bit&1][w];
    if (tot >= KSEL) cur = trial;
  }
  const float Tv = __uint_as_float(cur);
  const float lo = Tv*0.989f, hi = Tv*1.0115f;
  #pragma unroll
  for (int i=0;i<16;++i){
    float x = __uint_as_float(v[i]);
    if (x >= lo && x <= hi){
      int s = atomicAdd(&s_cnt, 1);
      if (s < BCAP) blist[b*BCAP + s] = n0 + i;
    }
  }
  __syncthreads();
  if (tid==0) bcnt[b] = (s_cnt < BCAP) ? s_cnt : BCAP;
}

// ---------------------------------------------------------------------------
// Exact fp32 recompute of combined for band members — 16 candidates/block.
// 512 threads = 16 groups of 32 lanes; group j owns candidate j. Feat rows
// staged in LDS (32 KB), read group-broadcast float4; Wa read coalesced from
// L2 and reused 16x per block (kills the 16x-redundant L2 Wa streaming that
// made the per-candidate version L2-BW-bound at ~74 us).
// ---------------------------------------------------------------------------
__global__ __launch_bounds__(512) void recomp_kernel(
    const float* __restrict__ feat, const float* __restrict__ Wa,
    const float* __restrict__ ba, const float* __restrict__ Wbr,
    const float* __restrict__ bbr, const float* __restrict__ mz,
    const int* __restrict__ bcnt, const int* __restrict__ blist,
    float* __restrict__ comb)
{
  __shared__ float fS[16][DD];       // 32 KB
  __shared__ int   s_n[16];
  const int tid = threadIdx.x;
  const int b  = blockIdx.x >> 8;            // 256 chunks per batch
  const int g0 = (blockIdx.x & 255) * 16;    // first candidate slot
  const int cnt = bcnt[b];
  if (g0 >= cnt) return;                     // whole chunk inactive
  if (tid < 16)
    s_n[tid] = (g0 + tid < cnt) ? blist[b*BCAP + g0 + tid] : -1;
  __syncthreads();
  // ---- stage up to 16 feat rows (coalesced float4)
  #pragma unroll
  for (int pass=0; pass<4; ++pass){
    const int j = pass*4 + (tid>>7);
    const int c4 = (tid & 127)*4;
    const int n = s_n[j];
    if (n >= 0){
      float4 v = *reinterpret_cast<const float4*>(feat + ((size_t)b*NP + n)*DD + c4);
      *reinterpret_cast<float4*>(&fS[j][c4]) = v;
    }
  }
  __syncthreads();

  const int grp = tid >> 5, l32 = tid & 31;
  if (s_n[grp] < 0) return;
  const int h0 = l32*4;            // h0..h0+3 and h0+128..h0+131
  float acc[8];
  #pragma unroll
  for (int i=0;i<8;++i) acc[i]=0.f;

  for (int d=0; d<DD; d+=4){
    const float4 f4 = *reinterpret_cast<const float4*>(&fS[grp][d]);
    const float fx[4] = {f4.x, f4.y, f4.z, f4.w};
    #pragma unroll
    for (int u=0; u<4; ++u){
      const float* wr = Wa + (size_t)(d+u)*HH;
      float4 wa0 = *reinterpret_cast<const float4*>(wr + h0);
      float4 wa1 = *reinterpret_cast<const float4*>(wr + 128 + h0);
      acc[0] += fx[u]*wa0.x; acc[1] += fx[u]*wa0.y;
      acc[2] += fx[u]*wa0.z; acc[3] += fx[u]*wa0.w;
      acc[4] += fx[u]*wa1.x; acc[5] += fx[u]*wa1.y;
      acc[6] += fx[u]*wa1.z; acc[7] += fx[u]*wa1.w;
    }
  }
  // epilogue: relu + Wbr, group reduction over 32 lanes
  float p0 = 0.f, p1 = 0.f;
  #pragma unroll
  for (int i=0;i<8;++i){
    const int h = (i<4) ? (h0+i) : (128 + h0 + (i-4));
    float x = fmaxf(acc[i] + ba[h], 0.f);
    p0 += x * Wbr[h];
    p1 += x * Wbr[HH+h];
  }
  #pragma unroll
  for (int off=1; off<32; off<<=1){ p0+=__shfl_xor(p0,off); p1+=__shfl_xor(p1,off); }
  if (l32==0){
    const float m0 = mz[b*4+0], iz0 = mz[b*4+1], m1 = mz[b*4+2], iz1 = mz[b*4+3];
    float l0 = p0 + bbr[0];
    float l1 = p1 + bbr[1];
    comb[(size_t)b*NP + s_n[grp]] = 0.5f*(expf(l0-m0)*iz0 + expf(l1-m1)*iz1);
  }
}

// ---------------------------------------------------------------------------
// Exact top-k selection on refined combined. (unchanged — proven)
// ---------------------------------------------------------------------------
__global__ __launch_bounds__(1024) void select_kernel(
    const float* __restrict__ comb, float* __restrict__ outIdxF,
    int* __restrict__ selIdx)
{
  __shared__ unsigned s_red[2][16];
  __shared__ unsigned s_wsum[16];
  const int tid = threadIdx.x;
  const int b = blockIdx.x;
  const int lane = tid & 63, wid = tid >> 6;
  const float* row = comb + (size_t)b*NP;

  unsigned v[16];
  {
    const float4* rp = reinterpret_cast<const float4*>(row + tid*16);
    #pragma unroll
    for (int g=0; g<4; ++g){
      float4 q = rp[g];
      v[g*4+0]=__float_as_uint(q.x);
      v[g*4+1]=__float_as_uint(q.y);
      v[g*4+2]=__float_as_uint(q.z);
      v[g*4+3]=__float_as_uint(q.w);
    }
  }
  unsigned cur = 0;
  #pragma unroll 1
  for (int bit=31; bit>=0; --bit){
    unsigned trial = cur | (1u<<bit);
    int c = 0;
    #pragma unroll
    for (int i=0;i<16;++i) c += (v[i] >= trial) ? 1 : 0;
    #pragma unroll
    for (int off=1; off<64; off<<=1) c += __shfl_xor(c, off);
    if (lane==0) s_red[bit&1][wid] = (unsigned)c;
    __syncthreads();
    unsigned tot=0;
    #pragma unroll
    for (int w=0;w<16;++w) tot += s_red[bit&1][w];
    if (tot >= KSEL) cur = trial;
  }
  const unsigned T = cur;
  {
    int c = 0;
    #pragma unroll
    for (int i=0;i<16;++i) c += (v[i] > T) ? 1 : 0;
    #pragma unroll
    for (int off=1; off<64; off<<=1) c += __shfl_xor(c, off);
    if (lane==0) s_red[1][wid] = (unsigned)c;
  }
  __syncthreads();
  unsigned gtot=0;
  #pragma unroll
  for (int w=0;w<16;++w) gtot += s_red[1][w];
  const int extra = KSEL - (int)gtot;

  int eqc=0;
  #pragma unroll
  for (int i=0;i<16;++i) eqc += (v[i]==T) ? 1 : 0;
  unsigned inc = (unsigned)eqc;
  #pragma unroll
  for (int off=1; off<64; off<<=1){
    unsigned o = __shfl_up(inc, off);
    if (lane >= off) inc += o;
  }
  if (lane==63) s_wsum[wid] = inc;
  __syncthreads();
  unsigned wbase = 0;
  for (int w=0; w<wid; ++w) wbase += s_wsum[w];
  const int eqBase = (int)(wbase + inc) - eqc;

  int eq=eqBase, sc=0;
  #pragma unroll
  for (int i=0;i<16;++i){
    unsigned x = v[i];
    if (x==T){ if (eq<extra) sc++; eq++; }
    else if (x>T) sc++;
  }
  unsigned inc2 = (unsigned)sc;
  #pragma unroll
  for (int off=1; off<64; off<<=1){
    unsigned o = __shfl_up(inc2, off);
    if (lane >= off) inc2 += o;
  }
  __syncthreads();
  if (lane==63) s_wsum[wid] = inc2;
  __syncthreads();
  unsigned wbase2 = 0;
  for (int w=0; w<wid; ++w) wbase2 += s_wsum[w];
  int pos = (int)(wbase2 + inc2) - sc;

  eq=eqBase;
  #pragma unroll
  for (int i=0;i<16;++i){
    unsigned x = v[i];
    int f=0;
    if (x==T){ if (eq<extra) f=1; eq++; }
    else if (x>T) f=1;
    if (f){
      int n = tid*16 + i;
      outIdxF[(size_t)b*KSEL + pos] = (float)n;
      selIdx[(size_t)b*KSEL + pos] = n;
      pos++;
    }
  }
}

// ---------------------------------------------------------------------------
// Gather selected rows. (unchanged — proven)
// ---------------------------------------------------------------------------
__global__ __launch_bounds__(256) void gather_kernel(
    const float* __restrict__ feat, const int* __restrict__ selIdx,
    float* __restrict__ outSel)
{
  const int tid = threadIdx.x;
  const int row = blockIdx.x*2 + (tid>>7);
  const int c4 = tid & 127;
  const int b = row / KSEL;
  const int idx = selIdx[row];
  const float4 v = *reinterpret_cast<const float4*>(feat + ((size_t)b*NP + idx)*DD + c4*4);
  *reinterpret_cast<float4*>(outSel + (size_t)row*DD + c4*4) = v;
}

// ---------------------------------------------------------------------------
// Per-(b,c) top-8/bottom-8 on attn computed on the fly from aL + mz
// (identical float ops as materialized attn -> identical bits/ties).
// ---------------------------------------------------------------------------
__global__ __launch_bounds__(256) void top16_kernel(
    const float* __restrict__ aL, const float* __restrict__ mz,
    int* __restrict__ top16)
{
  __shared__ unsigned long long wkT[4][8];
  __shared__ unsigned long long wkB[4][8];
  const int tid = threadIdx.x;
  const int bid = blockIdx.x;                // r = b*2 + c
  const int lane = tid & 63, wid = tid >> 6;
  const float* a = aL + (size_t)bid*NP;
  const float m = mz[bid*2+0], iz = mz[bid*2+1];

  unsigned long long t8[8], b8[8];
  #pragma unroll
  for (int i=0;i<8;++i){ t8[i]=0ull; b8[i]=~0ull; }

  for (int j=0;j<16;++j){
    const int n4 = tid + 256*j;
    const float4 v = *reinterpret_cast<const float4*>(a + 4*n4);
    float xs[4];
    xs[0] = expf(v.x-m)*iz; xs[1] = expf(v.y-m)*iz;
    xs[2] = expf(v.z-m)*iz; xs[3] = expf(v.w-m)*iz;
    #pragma unroll
    for (int q=0;q<4;++q){
      const int n = 4*n4 + q;
      const unsigned vb = __float_as_uint(xs[q]);
      unsigned long long kt = ((unsigned long long)vb<<32) | (unsigned)(NP-1-n);
      if (kt > t8[7]){
        t8[7]=kt;
        #pragma unroll
        for (int i=7;i>0;--i){ if (t8[i]>t8[i-1]){ unsigned long long t=t8[i-1]; t8[i-1]=t8[i]; t8[i]=t; } }
      }
      unsigned long long kb = ((unsigned long long)vb<<32) | (unsigned)n;
      if (kb < b8[7]){
        b8[7]=kb;
        #pragma unroll
        for (int i=7;i>0;--i){ if (b8[i]<b8[i-1]){ unsigned long long t=b8[i-1]; b8[i-1]=b8[i]; b8[i]=t; } }
      }
    }
  }

  #pragma unroll
  for (int pick=0; pick<8; ++pick){
    unsigned long long loc = t8[0];
    #pragma unroll
    for (int i=1;i<8;++i) loc = t8[i]>loc ? t8[i] : loc;
    #pragma unroll
    for (int off=1; off<64; off<<=1){ unsigned long long o=__shfl_xor(loc,off); loc=o>loc?o:loc; }
    if (lane==0) wkT[wid][pick]=loc;
    #pragma unroll
    for (int i=0;i<8;++i) if (t8[i]==loc) t8[i]=0ull;
  }
  #pragma unroll
  for (int pick=0; pick<8; ++pick){
    unsigned long long loc = b8[0];
    #pragma unroll
    for (int i=1;i<8;++i) loc = b8[i]<loc ? b8[i] : loc;
    #pragma unroll
    for (int off=1; off<64; off<<=1){ unsigned long long o=__shfl_xor(loc,off); loc=o<loc?o:loc; }
    if (lane==0) wkB[wid][pick]=loc;
    #pragma unroll
    for (int i=0;i<8;++i) if (b8[i]==loc) b8[i]=~0ull;
  }
  __syncthreads();

  if (wid==0){
    unsigned long long k = (lane<32) ? wkT[lane>>3][lane&7] : 0ull;
    #pragma unroll
    for (int pick=0; pick<8; ++pick){
      unsigned long long loc = k;
      #pragma unroll
      for (int off=1; off<64; off<<=1){ unsigned long long o=__shfl_xor(loc,off); loc=o>loc?o:loc; }
      if (k==loc) k=0ull;
      if (lane==0) top16[bid*16+pick] = NP-1-(int)(loc & 0xFFFFFFFFull);
    }
    unsigned long long kb = (lane<32) ? wkB[lane>>3][lane&7] : ~0ull;
    #pragma unroll
    for (int pick=0; pick<8; ++pick){
      unsigned long long loc = kb;
      #pragma unroll
      for (int off=1; off<64; off<<=1){ unsigned long long o=__shfl_xor(loc,off); loc=o<loc?o:loc; }
      if (kb==loc) kb=~0ull;
      if (lane==0) top16[bid*16+8+pick] = (int)(loc & 0xFFFFFFFFull);
    }
  }
}

// ---------------------------------------------------------------------------
// Instance MLP + CE partial, one block per (b,c,r). (unchanged — proven)
// ---------------------------------------------------------------------------
__global__ __launch_bounds__(256) void mlp_kernel(
    const float* __restrict__ feat, const float* __restrict__ W1,
    const float* __restrict__ b1, const float* __restrict__ W2,
    const float* __restrict__ b2, const int* __restrict__ top16,
    float* __restrict__ cews)
{
  __shared__ float fS[DD];
  __shared__ float r0[4], r1[4];
  const int tid = threadIdx.x;
  const int bid = blockIdx.x;
  const int r = bid & 15, c = (bid >> 4) & 1, b = bid >> 5;
  const int lane = tid & 63, wid = tid >> 6;
  const int gi = top16[(b*2+c)*16 + r];
  if (tid < 128){
    float4 v = *reinterpret_cast<const float4*>(feat + ((size_t)b*NP + gi)*DD + tid*4);
    *reinterpret_cast<float4*>(&fS[tid*4]) = v;
  }
  __syncthreads();
  const float* w1c = W1 + (size_t)c*DD*HH;
  float a0=0.f,a1=0.f,a2=0.f,a3=0.f;
  #pragma unroll 4
  for (int d=0; d<DD; d+=4){
    a0 += fS[d+0]*w1c[(size_t)(d+0)*HH + tid];
    a1 += fS[d+1]*w1c[(size_t)(d+1)*HH + tid];
    a2 += fS[d+2]*w1c[(size_t)(d+2)*HH + tid];
    a3 += fS[d+3]*w1c[(size_t)(d+3)*HH + tid];
  }
  float h = fmaxf((a0+a1)+(a2+a3) + b1[c*HH+tid], 0.f);
  float p0 = h*W2[(size_t)(c*HH+tid)*2 + 0];
  float p1 = h*W2[(size_t)(c*HH+tid)*2 + 1];
  #pragma unroll
  for (int off=1; off<64; off<<=1){ p0+=__shfl_xor(p0,off); p1+=__shfl_xor(p1,off); }
  if (lane==0){ r0[wid]=p0; r1[wid]=p1; }
  __syncthreads();
  if (tid==0){
    float l0 = (r0[0]+r0[1])+(r0[2]+r0[3]) + b2[c*2+0];
    float l1 = (r1[0]+r1[1])+(r1[2]+r1[3]) + b2[c*2+1];
    float mm = fmaxf(l0,l1);
    float lse = mm + logf(expf(l0-mm)+expf(l1-mm));
    float chosen = (r<8) ? l1 : l0;
    cews[bid] = lse - chosen;
  }
}

__global__ void loss_kernel(const float* __restrict__ cews, float* __restrict__ out_loss){
  if (threadIdx.x==0 && blockIdx.x==0){
    float s=0.f;
    for (int i=0;i<128;++i) s += cews[i];
    out_loss[0] = s / 128.0f;
  }
}

extern "C" void kernel_launch(void* const* d_in, const int* in_sizes, int n_in,
                              void* d_out, int out_size, void* d_ws, size_t ws_size,
                              hipStream_t stream) {
  const float* feat = (const float*)d_in[0];
  const float* Wa   = (const float*)d_in[1];
  const float* ba   = (const float*)d_in[2];
  const float* Wbr  = (const float*)d_in[3];
  const float* bbr  = (const float*)d_in[4];
  const float* W1   = (const float*)d_in[5];
  const float* b1   = (const float*)d_in[6];
  const float* W2   = (const float*)d_in[7];
  const float* b2   = (const float*)d_in[8];
  float* out = (float*)d_out;
  float* ws  = (float*)d_ws;

  float* a_logits = ws + WS_ALOGIT;
  int*   selIdx   = (int*)(ws + WS_SELIDX);
  float* mz       = ws + WS_MZ;
  int*   bcnt     = (int*)(ws + WS_BCNT);
  int*   blist    = (int*)(ws + WS_BLIST);
  int*   top16    = (int*)(ws + WS_TOP16);
  float* cews     = ws + WS_CE;

  unsigned short* WaT = (unsigned short*)d_out;   // head of selected region;
                                                  // fully overwritten by gather

  hipLaunchKernelGGL(waconv_kernel, dim3(DD/32, HH/32), dim3(32,8), 0, stream,
                     Wa, WaT);
  hipLaunchKernelGGL(gemm_mfma_kernel, dim3(TOTP/128), dim3(512), 0, stream,
                     feat, WaT, ba, Wbr, bbr, a_logits);
  hipLaunchKernelGGL(smstat_kernel, dim3(NB*CC), dim3(1024), 0, stream,
                     a_logits, mz);
  hipLaunchKernelGGL(selTF_kernel, dim3(NB), dim3(1024), 0, stream,
                     a_logits, mz, out + OFF_COMB, bcnt, blist);
  hipLaunchKernelGGL(recomp_kernel, dim3(NB*256), dim3(512), 0, stream,
                     feat, Wa, ba, Wbr, bbr, mz, bcnt, blist, out + OFF_COMB);
  hipLaunchKernelGGL(select_kernel, dim3(NB), dim3(1024), 0, stream,
                     out + OFF_COMB, out + OFF_IDX, selIdx);
  hipLaunchKernelGGL(gather_kernel, dim3(NB*KSEL/2), dim3(256), 0, stream,
                     feat, selIdx, out);
  hipLaunchKernelGGL(top16_kernel, dim3(NB*CC), dim3(256), 0, stream,
                     a_logits, mz, top16);
  hipLaunchKernelGGL(mlp_kernel, dim3(NB*CC*16), dim3(256), 0, stream,
                     feat, W1, b1, W2, b2, top16, cews);
  hipLaunchKernelGGL(loss_kernel, dim3(1), dim3(64), 0, stream,
                     cews, out + OFF_LOSS);
}

// Round 7
// 257.067 us; speedup vs baseline: 1.4795x; 1.4795x over previous
//
#include <hip/hip_runtime.h>

#define NB 4
#define NP 16384
#define DD 512
#define HH 256
#define CC 2
#define KSEL 11468
#define TOTP (NB*NP)
#define BCAP 4096

// d_out offsets (floats)
#define OFF_COMB (NB*KSEL*DD)            // 23486464
#define OFF_IDX  (OFF_COMB + NB*NP)      // 23552000
#define OFF_LOSS (OFF_IDX + NB*KSEL)     // 23597872

// ws offsets (floats)
#define WS_ALOGIT 0
#define WS_SELIDX (2*NB*CC*NP)               // 262144 (ints)
#define WS_MZ     (WS_SELIDX + NB*KSEL)      // (16 floats)
#define WS_BCNT   (WS_MZ + 16)               // ints (4)
#define WS_BLIST  (WS_BCNT + 4)              // ints (4*BCAP)
#define WS_TOP16  (WS_BLIST + NB*BCAP)       // ints (8*16)
#define WS_CE     (WS_TOP16 + 128)           // floats (128)

typedef __attribute__((ext_vector_type(8))) short short8x;
typedef __attribute__((ext_vector_type(4))) float f32x4;

__device__ __forceinline__ unsigned short f2bf(float x){
  unsigned u = __float_as_uint(x);
  unsigned r = (u + 0x7FFFu + ((u >> 16) & 1u)) >> 16;
  return (unsigned short)r;
}

// ---------------------------------------------------------------------------
// Wa (512x256 f32) -> Wa_t (256x512 bf16), transposed, stored at d_out head.
// ---------------------------------------------------------------------------
__global__ __launch_bounds__(256) void waconv_kernel(
    const float* __restrict__ Wa, unsigned short* __restrict__ WaT)
{
  __shared__ float tile[32][33];
  const int tx = threadIdx.x, ty = threadIdx.y;   // 32 x 8
  const int k0 = blockIdx.x * 32, n0 = blockIdx.y * 32;
  #pragma unroll
  for (int i=0;i<4;++i)
    tile[ty+8*i][tx] = Wa[(size_t)(k0+ty+8*i)*HH + n0 + tx];
  __syncthreads();
  #pragma unroll
  for (int i=0;i<4;++i)
    WaT[(size_t)(n0+ty+8*i)*DD + k0 + tx] = f2bf(tile[tx][ty+8*i]);
}

// ---------------------------------------------------------------------------
// MFMA GEMM: a_logits[b,c,n] = Wbr[c].relu(f[n]@Wa+ba) + bbr[c], bf16 inputs.
// BM=128, BN=256(full H), BK=64; 8 waves (2M x 4N), wave tile 64x64.
// (unchanged — proven)
// ---------------------------------------------------------------------------
__global__ __launch_bounds__(512) void gemm_mfma_kernel(
    const float* __restrict__ feat, const unsigned short* __restrict__ WaT,
    const float* __restrict__ ba, const float* __restrict__ Wbr,
    const float* __restrict__ bbr, float* __restrict__ aL)
{
  __shared__ __attribute__((aligned(16))) unsigned char smem[65536];
  __shared__ float sBA[HH], sW0[HH], sW1[HH];
  unsigned char* sA = smem;                 // 128*64 bf16 = 16 KB (swizzled)
  unsigned char* sB = smem + 16384;         // 256*64 bf16 = 32 KB (swizzled)

  const int tid  = threadIdx.x;
  const int lane = tid & 63;
  const int wid  = tid >> 6;
  const int wm = wid >> 2, wn = wid & 3;
  const int fr = lane & 15, fq = lane >> 4;
  const int p0 = blockIdx.x * 128;
  const float bb0 = bbr[0], bb1 = bbr[1];

  if (tid < HH){ sBA[tid] = ba[tid]; sW0[tid] = Wbr[tid]; sW1[tid] = Wbr[HH+tid]; }

  f32x4 acc[4][4];
  #pragma unroll
  for (int i=0;i<4;++i)
    #pragma unroll
    for (int j=0;j<4;++j)
      acc[i][j] = (f32x4){0.f,0.f,0.f,0.f};

  const int am = tid >> 2, akq = (tid & 3) * 16;     // A staging: row, k-offset
  const int bn = tid >> 1, bhf = tid & 1;            // B staging

  for (int k0 = 0; k0 < DD; k0 += 64){
    __syncthreads();
    // ---- stage A: 128x64 fp32 -> bf16, swizzled K-major
    {
      const float4* src = reinterpret_cast<const float4*>(
          feat + (size_t)(p0 + am)*DD + k0 + akq);
      float4 v0 = src[0], v1 = src[1], v2 = src[2], v3 = src[3];
      unsigned short u[16];
      u[0]=f2bf(v0.x); u[1]=f2bf(v0.y); u[2]=f2bf(v0.z); u[3]=f2bf(v0.w);
      u[4]=f2bf(v1.x); u[5]=f2bf(v1.y); u[6]=f2bf(v1.z); u[7]=f2bf(v1.w);
      u[8]=f2bf(v2.x); u[9]=f2bf(v2.y); u[10]=f2bf(v2.z); u[11]=f2bf(v2.w);
      u[12]=f2bf(v3.x); u[13]=f2bf(v3.y); u[14]=f2bf(v3.z); u[15]=f2bf(v3.w);
      uint4 w0, w1;
      w0.x = (unsigned)u[0] | ((unsigned)u[1]<<16);
      w0.y = (unsigned)u[2] | ((unsigned)u[3]<<16);
      w0.z = (unsigned)u[4] | ((unsigned)u[5]<<16);
      w0.w = (unsigned)u[6] | ((unsigned)u[7]<<16);
      w1.x = (unsigned)u[8] | ((unsigned)u[9]<<16);
      w1.y = (unsigned)u[10] | ((unsigned)u[11]<<16);
      w1.z = (unsigned)u[12] | ((unsigned)u[13]<<16);
      w1.w = (unsigned)u[14] | ((unsigned)u[15]<<16);
      const int swz = (am & 7) << 4;
      *reinterpret_cast<uint4*>(sA + (((am*128) + akq*2) ^ swz)) = w0;
      *reinterpret_cast<uint4*>(sA + (((am*128) + akq*2 + 16) ^ swz)) = w1;
    }
    // ---- stage B: 256x64 bf16 from WaT, swizzled K-major
    {
      const uint4* src = reinterpret_cast<const uint4*>(
          WaT + (size_t)bn*DD + k0 + bhf*32);
      uint4 q0 = src[0], q1 = src[1], q2 = src[2], q3 = src[3];
      const int swz = (bn & 7) << 4;
      const int base = bn*128 + bhf*64;
      *reinterpret_cast<uint4*>(sB + ((base     ) ^ swz)) = q0;
      *reinterpret_cast<uint4*>(sB + ((base + 16) ^ swz)) = q1;
      *reinterpret_cast<uint4*>(sB + ((base + 32) ^ swz)) = q2;
      *reinterpret_cast<uint4*>(sB + ((base + 48) ^ swz)) = q3;
    }
    __syncthreads();
    // ---- MFMA
    #pragma unroll
    for (int kf = 0; kf < 2; ++kf){
      short8x af[4], bf[4];
      #pragma unroll
      for (int mf = 0; mf < 4; ++mf){
        int m_loc = wm*64 + mf*16 + fr;
        int off = ((m_loc*128 + kf*64 + fq*16) ^ ((m_loc & 7) << 4));
        af[mf] = *reinterpret_cast<const short8x*>(sA + off);
      }
      #pragma unroll
      for (int nf = 0; nf < 4; ++nf){
        int n_loc = wn*64 + nf*16 + fr;
        int off = ((n_loc*128 + kf*64 + fq*16) ^ ((n_loc & 7) << 4));
        bf[nf] = *reinterpret_cast<const short8x*>(sB + off);
      }
      #pragma unroll
      for (int mf = 0; mf < 4; ++mf)
        #pragma unroll
        for (int nf = 0; nf < 4; ++nf)
          acc[mf][nf] = __builtin_amdgcn_mfma_f32_16x16x32_bf16(
              af[mf], bf[nf], acc[mf][nf], 0, 0, 0);
    }
  }
  __syncthreads();

  // ---- epilogue: relu + Wbr projection via LDS h-tile, M in halves of 64
  float* hS = reinterpret_cast<float*>(smem);
  #pragma unroll
  for (int mh = 0; mh < 2; ++mh){
    if (wm == mh){
      #pragma unroll
      for (int mf = 0; mf < 4; ++mf)
        #pragma unroll
        for (int nf = 0; nf < 4; ++nf)
          #pragma unroll
          for (int r = 0; r < 4; ++r){
            int row = mf*16 + fq*4 + r;
            int col = wn*64 + nf*16 + fr;
            hS[row*256 + col] = acc[mf][nf][r];
          }
    }
    __syncthreads();
    {
      const int row = tid >> 3, cg = tid & 7;
      float s0 = 0.f, s1 = 0.f;
      #pragma unroll
      for (int j = 0; j < 8; ++j){
        int col = cg*4 + j*32;
        float4 hv = *reinterpret_cast<const float4*>(&hS[row*256 + col]);
        float xs[4] = {hv.x, hv.y, hv.z, hv.w};
        #pragma unroll
        for (int u = 0; u < 4; ++u){
          int ccol = col + u;
          float x = fmaxf(xs[u] + sBA[ccol], 0.f);
          s0 += x * sW0[ccol];
          s1 += x * sW1[ccol];
        }
      }
      s0 += __shfl_xor(s0,1); s1 += __shfl_xor(s1,1);
      s0 += __shfl_xor(s0,2); s1 += __shfl_xor(s1,2);
      s0 += __shfl_xor(s0,4); s1 += __shfl_xor(s1,4);
      if (cg == 0){
        int p = p0 + mh*64 + row;
        int b = p >> 14, nl = p & (NP-1);
        aL[((size_t)b*CC + 0)*NP + nl] = s0 + bb0;
        aL[((size_t)b*CC + 1)*NP + nl] = s1 + bb1;
      }
    }
    __syncthreads();
  }
}

// ---------------------------------------------------------------------------
// Per-(b,c) row max + 1/Z (double accum). One block per row (8 blocks).
// (unchanged — proven)
// ---------------------------------------------------------------------------
__global__ __launch_bounds__(1024) void smstat_kernel(
    const float* __restrict__ aL, float* __restrict__ mz)
{
  __shared__ float  s_redf[16];
  __shared__ double s_redd[16];
  __shared__ float  s_max;
  const int tid = threadIdx.x;
  const int lane = tid & 63, wid = tid >> 6;
  const int r = blockIdx.x;                 // r = b*2 + c
  const float* a = aL + (size_t)r*NP;
  float m = -1e30f;
  for (int n=tid; n<NP; n+=1024) m = fmaxf(m, a[n]);
  #pragma unroll
  for (int off=1; off<64; off<<=1) m = fmaxf(m, __shfl_xor(m, off));
  if (lane==0) s_redf[wid]=m;
  __syncthreads();
  if (tid==0){ float mm=s_redf[0]; for(int w=1;w<16;++w) mm=fmaxf(mm,s_redf[w]); s_max=mm; }
  __syncthreads();
  m = s_max;
  double ls = 0.0;
  for (int n=tid;n<NP;n+=1024) ls += (double)expf(a[n]-m);
  #pragma unroll
  for (int off=1; off<64; off<<=1) ls += __shfl_xor(ls, off);
  if (lane==0) s_redd[wid]=ls;
  __syncthreads();
  if (tid==0){
    double t=0; for(int w=0;w<16;++w) t+=s_redd[w];
    mz[r*2+0]=m; mz[r*2+1]=(float)(1.0/t);
  }
}

// ---------------------------------------------------------------------------
// Fused: combined finalize + approx threshold radix + band list.
// (unchanged — proven)
// ---------------------------------------------------------------------------
__global__ __launch_bounds__(1024) void selTF_kernel(
    const float* __restrict__ aL, const float* __restrict__ mz,
    float* __restrict__ comb, int* __restrict__ bcnt, int* __restrict__ blist)
{
  __shared__ unsigned s_red[2][16];
  __shared__ int s_cnt;
  const int tid = threadIdx.x;
  const int b = blockIdx.x;
  const int lane = tid & 63, wid = tid >> 6;
  const float m0 = mz[b*4+0], iz0 = mz[b*4+1], m1 = mz[b*4+2], iz1 = mz[b*4+3];
  const float* a0 = aL + ((size_t)b*CC + 0)*NP;
  const float* a1 = aL + ((size_t)b*CC + 1)*NP;
  float* oc = comb + (size_t)b*NP;
  const int n0 = tid*16;

  unsigned v[16];
  #pragma unroll
  for (int g=0; g<4; ++g){
    float4 qa = *reinterpret_cast<const float4*>(a0 + n0 + g*4);
    float4 qb = *reinterpret_cast<const float4*>(a1 + n0 + g*4);
    float4 CV;
    CV.x = 0.5f*(expf(qa.x-m0)*iz0 + expf(qb.x-m1)*iz1);
    CV.y = 0.5f*(expf(qa.y-m0)*iz0 + expf(qb.y-m1)*iz1);
    CV.z = 0.5f*(expf(qa.z-m0)*iz0 + expf(qb.z-m1)*iz1);
    CV.w = 0.5f*(expf(qa.w-m0)*iz0 + expf(qb.w-m1)*iz1);
    *reinterpret_cast<float4*>(oc + n0 + g*4) = CV;
    v[g*4+0]=__float_as_uint(CV.x);
    v[g*4+1]=__float_as_uint(CV.y);
    v[g*4+2]=__float_as_uint(CV.z);
    v[g*4+3]=__float_as_uint(CV.w);
  }
  if (tid==0) s_cnt = 0;

  unsigned cur = 0;
  #pragma unroll 1
  for (int bit=31; bit>=12; --bit){
    unsigned trial = cur | (1u<<bit);
    int c = 0;
    #pragma unroll
    for (int i=0;i<16;++i) c += (v[i] >= trial) ? 1 : 0;
    #pragma unroll
    for (int off=1; off<64; off<<=1) c += __shfl_xor(c, off);
    if (lane==0) s_red[bit&1][wid] = (unsigned)c;
    __syncthreads();
    unsigned tot=0;
    #pragma unroll
    for (int w=0;w<16;++w) tot += s_red[bit&1][w];
    if (tot >= KSEL) cur = trial;
  }
  const float Tv = __uint_as_float(cur);
  const float lo = Tv*0.989f, hi = Tv*1.0115f;
  #pragma unroll
  for (int i=0;i<16;++i){
    float x = __uint_as_float(v[i]);
    if (x >= lo && x <= hi){
      int s = atomicAdd(&s_cnt, 1);
      if (s < BCAP) blist[b*BCAP + s] = n0 + i;
    }
  }
  __syncthreads();
  if (tid==0) bcnt[b] = (s_cnt < BCAP) ? s_cnt : BCAP;
}

// ---------------------------------------------------------------------------
// Exact fp32 recompute of combined for band members — 16 candidates/block,
// GEMM-tiled: Wa staged through LDS in 16 tiles of [32][256] (read ONCE per
// block from L2: 512 KB/block, ~100 MB total vs round-6's 4 MB/block which
// was per-wave L2 re-streaming and landed at 178 us). All LDS reads are
// conflict-free (consecutive-lane 16B for waS; fS is 2-addr broadcast).
// Accumulation order identical to the round-6-proven kernel (d-sequential
// chain per h, same epilogue reduction).
// ---------------------------------------------------------------------------
__global__ __launch_bounds__(512) void recomp_kernel(
    const float* __restrict__ feat, const float* __restrict__ Wa,
    const float* __restrict__ ba, const float* __restrict__ Wbr,
    const float* __restrict__ bbr, const float* __restrict__ mz,
    const int* __restrict__ bcnt, const int* __restrict__ blist,
    float* __restrict__ comb)
{
  __shared__ float fS[16][DD];       // 32 KB: 16 candidate rows
  __shared__ float waS[32][HH];      // 32 KB: one Wa k-tile
  __shared__ int   s_n[16];
  const int tid = threadIdx.x;
  const int b  = blockIdx.x >> 8;            // 256 chunks per batch
  const int g0 = (blockIdx.x & 255) * 16;    // first candidate slot
  const int cnt = bcnt[b];
  if (g0 >= cnt) return;                     // whole chunk inactive
  if (tid < 16)
    s_n[tid] = (g0 + tid < cnt) ? blist[b*BCAP + g0 + tid] : -1;
  __syncthreads();
  // ---- stage up to 16 feat rows (coalesced float4)
  #pragma unroll
  for (int pass=0; pass<4; ++pass){
    const int j = pass*4 + (tid>>7);
    const int c4 = (tid & 127)*4;
    const int n = s_n[j];
    if (n >= 0){
      float4 v = *reinterpret_cast<const float4*>(feat + ((size_t)b*NP + n)*DD + c4);
      *reinterpret_cast<float4*>(&fS[j][c4]) = v;
    }
  }

  const int grp = tid >> 5, l32 = tid & 31;
  const int h0 = l32*4;            // owns h0..h0+3 and 128+h0..128+h0+3
  const bool active = true;        // refined below after staging barriers
  float acc[8];
  #pragma unroll
  for (int i=0;i<8;++i) acc[i]=0.f;

  #pragma unroll 1
  for (int kt=0; kt<16; ++kt){
    __syncthreads();               // waS free to overwrite; also covers feat/s_n on kt=0
    // ---- stage Wa rows kt*32..kt*32+31 (32x256 f32 = 2048 float4, 4/thread)
    {
      const float4* src = reinterpret_cast<const float4*>(Wa + (size_t)(kt*32)*HH);
      float4* dst = reinterpret_cast<float4*>(&waS[0][0]);
      #pragma unroll
      for (int q=0; q<4; ++q) dst[tid + 512*q] = src[tid + 512*q];
    }
    __syncthreads();
    if (s_n[grp] >= 0){
      #pragma unroll
      for (int kk4=0; kk4<8; ++kk4){
        const float4 fv = *reinterpret_cast<const float4*>(&fS[grp][kt*32 + kk4*4]);
        const float fx[4] = {fv.x, fv.y, fv.z, fv.w};
        #pragma unroll
        for (int u=0; u<4; ++u){
          const int kk = kk4*4 + u;
          float4 w0 = *reinterpret_cast<const float4*>(&waS[kk][h0]);
          float4 w1 = *reinterpret_cast<const float4*>(&waS[kk][128 + h0]);
          acc[0] += fx[u]*w0.x; acc[1] += fx[u]*w0.y;
          acc[2] += fx[u]*w0.z; acc[3] += fx[u]*w0.w;
          acc[4] += fx[u]*w1.x; acc[5] += fx[u]*w1.y;
          acc[6] += fx[u]*w1.z; acc[7] += fx[u]*w1.w;
        }
      }
    }
  }
  if (s_n[grp] < 0) return;
  // ---- epilogue: relu + Wbr, group reduction over 32 lanes (proven, r6)
  float p0 = 0.f, p1 = 0.f;
  #pragma unroll
  for (int i=0;i<8;++i){
    const int h = (i<4) ? (h0+i) : (128 + h0 + (i-4));
    float x = fmaxf(acc[i] + ba[h], 0.f);
    p0 += x * Wbr[h];
    p1 += x * Wbr[HH+h];
  }
  #pragma unroll
  for (int off=1; off<32; off<<=1){ p0+=__shfl_xor(p0,off); p1+=__shfl_xor(p1,off); }
  if (l32==0){
    const float m0 = mz[b*4+0], iz0 = mz[b*4+1], m1 = mz[b*4+2], iz1 = mz[b*4+3];
    float l0 = p0 + bbr[0];
    float l1 = p1 + bbr[1];
    comb[(size_t)b*NP + s_n[grp]] = 0.5f*(expf(l0-m0)*iz0 + expf(l1-m1)*iz1);
  }
}

// ---------------------------------------------------------------------------
// Exact top-k selection on refined combined. (unchanged — proven)
// ---------------------------------------------------------------------------
__global__ __launch_bounds__(1024) void select_kernel(
    const float* __restrict__ comb, float* __restrict__ outIdxF,
    int* __restrict__ selIdx)
{
  __shared__ unsigned s_red[2][16];
  __shared__ unsigned s_wsum[16];
  const int tid = threadIdx.x;
  const int b = blockIdx.x;
  const int lane = tid & 63, wid = tid >> 6;
  const float* row = comb + (size_t)b*NP;

  unsigned v[16];
  {
    const float4* rp = reinterpret_cast<const float4*>(row + tid*16);
    #pragma unroll
    for (int g=0; g<4; ++g){
      float4 q = rp[g];
      v[g*4+0]=__float_as_uint(q.x);
      v[g*4+1]=__float_as_uint(q.y);
      v[g*4+2]=__float_as_uint(q.z);
      v[g*4+3]=__float_as_uint(q.w);
    }
  }
  unsigned cur = 0;
  #pragma unroll 1
  for (int bit=31; bit>=0; --bit){
    unsigned trial = cur | (1u<<bit);
    int c = 0;
    #pragma unroll
    for (int i=0;i<16;++i) c += (v[i] >= trial) ? 1 : 0;
    #pragma unroll
    for (int off=1; off<64; off<<=1) c += __shfl_xor(c, off);
    if (lane==0) s_red[bit&1][wid] = (unsigned)c;
    __syncthreads();
    unsigned tot=0;
    #pragma unroll
    for (int w=0;w<16;++w) tot += s_red[bit&1][w];
    if (tot >= KSEL) cur = trial;
  }
  const unsigned T = cur;
  {
    int c = 0;
    #pragma unroll
    for (int i=0;i<16;++i) c += (v[i] > T) ? 1 : 0;
    #pragma unroll
    for (int off=1; off<64; off<<=1) c += __shfl_xor(c, off);
    if (lane==0) s_red[1][wid] = (unsigned)c;
  }
  __syncthreads();
  unsigned gtot=0;
  #pragma unroll
  for (int w=0;w<16;++w) gtot += s_red[1][w];
  const int extra = KSEL - (int)gtot;

  int eqc=0;
  #pragma unroll
  for (int i=0;i<16;++i) eqc += (v[i]==T) ? 1 : 0;
  unsigned inc = (unsigned)eqc;
  #pragma unroll
  for (int off=1; off<64; off<<=1){
    unsigned o = __shfl_up(inc, off);
    if (lane >= off) inc += o;
  }
  if (lane==63) s_wsum[wid] = inc;
  __syncthreads();
  unsigned wbase = 0;
  for (int w=0; w<wid; ++w) wbase += s_wsum[w];
  const int eqBase = (int)(wbase + inc) - eqc;

  int eq=eqBase, sc=0;
  #pragma unroll
  for (int i=0;i<16;++i){
    unsigned x = v[i];
    if (x==T){ if (eq<extra) sc++; eq++; }
    else if (x>T) sc++;
  }
  unsigned inc2 = (unsigned)sc;
  #pragma unroll
  for (int off=1; off<64; off<<=1){
    unsigned o = __shfl_up(inc2, off);
    if (lane >= off) inc2 += o;
  }
  __syncthreads();
  if (lane==63) s_wsum[wid] = inc2;
  __syncthreads();
  unsigned wbase2 = 0;
  for (int w=0; w<wid; ++w) wbase2 += s_wsum[w];
  int pos = (int)(wbase2 + inc2) - sc;

  eq=eqBase;
  #pragma unroll
  for (int i=0;i<16;++i){
    unsigned x = v[i];
    int f=0;
    if (x==T){ if (eq<extra) f=1; eq++; }
    else if (x>T) f=1;
    if (f){
      int n = tid*16 + i;
      outIdxF[(size_t)b*KSEL + pos] = (float)n;
      selIdx[(size_t)b*KSEL + pos] = n;
      pos++;
    }
  }
}

// ---------------------------------------------------------------------------
// Gather selected rows. (unchanged — proven)
// ---------------------------------------------------------------------------
__global__ __launch_bounds__(256) void gather_kernel(
    const float* __restrict__ feat, const int* __restrict__ selIdx,
    float* __restrict__ outSel)
{
  const int tid = threadIdx.x;
  const int row = blockIdx.x*2 + (tid>>7);
  const int c4 = tid & 127;
  const int b = row / KSEL;
  const int idx = selIdx[row];
  const float4 v = *reinterpret_cast<const float4*>(feat + ((size_t)b*NP + idx)*DD + c4*4);
  *reinterpret_cast<float4*>(outSel + (size_t)row*DD + c4*4) = v;
}

// ---------------------------------------------------------------------------
// Per-(b,c) top-8/bottom-8 on attn computed on the fly from aL + mz.
// (unchanged — proven)
// ---------------------------------------------------------------------------
__global__ __launch_bounds__(256) void top16_kernel(
    const float* __restrict__ aL, const float* __restrict__ mz,
    int* __restrict__ top16)
{
  __shared__ unsigned long long wkT[4][8];
  __shared__ unsigned long long wkB[4][8];
  const int tid = threadIdx.x;
  const int bid = blockIdx.x;                // r = b*2 + c
  const int lane = tid & 63, wid = tid >> 6;
  const float* a = aL + (size_t)bid*NP;
  const float m = mz[bid*2+0], iz = mz[bid*2+1];

  unsigned long long t8[8], b8[8];
  #pragma unroll
  for (int i=0;i<8;++i){ t8[i]=0ull; b8[i]=~0ull; }

  for (int j=0;j<16;++j){
    const int n4 = tid + 256*j;
    const float4 v = *reinterpret_cast<const float4*>(a + 4*n4);
    float xs[4];
    xs[0] = expf(v.x-m)*iz; xs[1] = expf(v.y-m)*iz;
    xs[2] = expf(v.z-m)*iz; xs[3] = expf(v.w-m)*iz;
    #pragma unroll
    for (int q=0;q<4;++q){
      const int n = 4*n4 + q;
      const unsigned vb = __float_as_uint(xs[q]);
      unsigned long long kt = ((unsigned long long)vb<<32) | (unsigned)(NP-1-n);
      if (kt > t8[7]){
        t8[7]=kt;
        #pragma unroll
        for (int i=7;i>0;--i){ if (t8[i]>t8[i-1]){ unsigned long long t=t8[i-1]; t8[i-1]=t8[i]; t8[i]=t; } }
      }
      unsigned long long kb = ((unsigned long long)vb<<32) | (unsigned)n;
      if (kb < b8[7]){
        b8[7]=kb;
        #pragma unroll
        for (int i=7;i>0;--i){ if (b8[i]<b8[i-1]){ unsigned long long t=b8[i-1]; b8[i-1]=b8[i]; b8[i]=t; } }
      }
    }
  }

  #pragma unroll
  for (int pick=0; pick<8; ++pick){
    unsigned long long loc = t8[0];
    #pragma unroll
    for (int i=1;i<8;++i) loc = t8[i]>loc ? t8[i] : loc;
    #pragma unroll
    for (int off=1; off<64; off<<=1){ unsigned long long o=__shfl_xor(loc,off); loc=o>loc?o:loc; }
    if (lane==0) wkT[wid][pick]=loc;
    #pragma unroll
    for (int i=0;i<8;++i) if (t8[i]==loc) t8[i]=0ull;
  }
  #pragma unroll
  for (int pick=0; pick<8; ++pick){
    unsigned long long loc = b8[0];
    #pragma unroll
    for (int i=1;i<8;++i) loc = b8[i]<loc ? b8[i] : loc;
    #pragma unroll
    for (int off=1; off<64; off<<=1){ unsigned long long o=__shfl_xor(loc,off); loc=o<loc?o:loc; }
    if (lane==0) wkB[wid][pick]=loc;
    #pragma unroll
    for (int i=0;i<8;++i) if (b8[i]==loc) b8[i]=~0ull;
  }
  __syncthreads();

  if (wid==0){
    unsigned long long k = (lane<32) ? wkT[lane>>3][lane&7] : 0ull;
    #pragma unroll
    for (int pick=0; pick<8; ++pick){
      unsigned long long loc = k;
      #pragma unroll
      for (int off=1; off<64; off<<=1){ unsigned long long o=__shfl_xor(loc,off); loc=o>loc?o:loc; }
      if (k==loc) k=0ull;
      if (lane==0) top16[bid*16+pick] = NP-1-(int)(loc & 0xFFFFFFFFull);
    }
    unsigned long long kb = (lane<32) ? wkB[lane>>3][lane&7] : ~0ull;
    #pragma unroll
    for (int pick=0; pick<8; ++pick){
      unsigned long long loc = kb;
      #pragma unroll
      for (int off=1; off<64; off<<=1){ unsigned long long o=__shfl_xor(loc,off); loc=o<loc?o:loc; }
      if (kb==loc) kb=~0ull;
      if (lane==0) top16[bid*16+8+pick] = (int)(loc & 0xFFFFFFFFull);
    }
  }
}

// ---------------------------------------------------------------------------
// Instance MLP + CE partial, one block per (b,c,r). (unchanged — proven)
// ---------------------------------------------------------------------------
__global__ __launch_bounds__(256) void mlp_kernel(
    const float* __restrict__ feat, const float* __restrict__ W1,
    const float* __restrict__ b1, const float* __restrict__ W2,
    const float* __restrict__ b2, const int* __restrict__ top16,
    float* __restrict__ cews)
{
  __shared__ float fS[DD];
  __shared__ float r0[4], r1[4];
  const int tid = threadIdx.x;
  const int bid = blockIdx.x;
  const int r = bid & 15, c = (bid >> 4) & 1, b = bid >> 5;
  const int lane = tid & 63, wid = tid >> 6;
  const int gi = top16[(b*2+c)*16 + r];
  if (tid < 128){
    float4 v = *reinterpret_cast<const float4*>(feat + ((size_t)b*NP + gi)*DD + tid*4);
    *reinterpret_cast<float4*>(&fS[tid*4]) = v;
  }
  __syncthreads();
  const float* w1c = W1 + (size_t)c*DD*HH;
  float a0=0.f,a1=0.f,a2=0.f,a3=0.f;
  #pragma unroll 4
  for (int d=0; d<DD; d+=4){
    a0 += fS[d+0]*w1c[(size_t)(d+0)*HH + tid];
    a1 += fS[d+1]*w1c[(size_t)(d+1)*HH + tid];
    a2 += fS[d+2]*w1c[(size_t)(d+2)*HH + tid];
    a3 += fS[d+3]*w1c[(size_t)(d+3)*HH + tid];
  }
  float h = fmaxf((a0+a1)+(a2+a3) + b1[c*HH+tid], 0.f);
  float p0 = h*W2[(size_t)(c*HH+tid)*2 + 0];
  float p1 = h*W2[(size_t)(c*HH+tid)*2 + 1];
  #pragma unroll
  for (int off=1; off<64; off<<=1){ p0+=__shfl_xor(p0,off); p1+=__shfl_xor(p1,off); }
  if (lane==0){ r0[wid]=p0; r1[wid]=p1; }
  __syncthreads();
  if (tid==0){
    float l0 = (r0[0]+r0[1])+(r0[2]+r0[3]) + b2[c*2+0];
    float l1 = (r1[0]+r1[1])+(r1[2]+r1[3]) + b2[c*2+1];
    float mm = fmaxf(l0,l1);
    float lse = mm + logf(expf(l0-mm)+expf(l1-mm));
    float chosen = (r<8) ? l1 : l0;
    cews[bid] = lse - chosen;
  }
}

__global__ void loss_kernel(const float* __restrict__ cews, float* __restrict__ out_loss){
  if (threadIdx.x==0 && blockIdx.x==0){
    float s=0.f;
    for (int i=0;i<128;++i) s += cews[i];
    out_loss[0] = s / 128.0f;
  }
}

extern "C" void kernel_launch(void* const* d_in, const int* in_sizes, int n_in,
                              void* d_out, int out_size, void* d_ws, size_t ws_size,
                              hipStream_t stream) {
  const float* feat = (const float*)d_in[0];
  const float* Wa   = (const float*)d_in[1];
  const float* ba   = (const float*)d_in[2];
  const float* Wbr  = (const float*)d_in[3];
  const float* bbr  = (const float*)d_in[4];
  const float* W1   = (const float*)d_in[5];
  const float* b1   = (const float*)d_in[6];
  const float* W2   = (const float*)d_in[7];
  const float* b2   = (const float*)d_in[8];
  float* out = (float*)d_out;
  float* ws  = (float*)d_ws;

  float* a_logits = ws + WS_ALOGIT;
  int*   selIdx   = (int*)(ws + WS_SELIDX);
  float* mz       = ws + WS_MZ;
  int*   bcnt     = (int*)(ws + WS_BCNT);
  int*   blist    = (int*)(ws + WS_BLIST);
  int*   top16    = (int*)(ws + WS_TOP16);
  float* cews     = ws + WS_CE;

  unsigned short* WaT = (unsigned short*)d_out;   // head of selected region;
                                                  // fully overwritten by gather

  hipLaunchKernelGGL(waconv_kernel, dim3(DD/32, HH/32), dim3(32,8), 0, stream,
                     Wa, WaT);
  hipLaunchKernelGGL(gemm_mfma_kernel, dim3(TOTP/128), dim3(512), 0, stream,
                     feat, WaT, ba, Wbr, bbr, a_logits);
  hipLaunchKernelGGL(smstat_kernel, dim3(NB*CC), dim3(1024), 0, stream,
                     a_logits, mz);
  hipLaunchKernelGGL(selTF_kernel, dim3(NB), dim3(1024), 0, stream,
                     a_logits, mz, out + OFF_COMB, bcnt, blist);
  hipLaunchKernelGGL(recomp_kernel, dim3(NB*256), dim3(512), 0, stream,
                     feat, Wa, ba, Wbr, bbr, mz, bcnt, blist, out + OFF_COMB);
  hipLaunchKernelGGL(select_kernel, dim3(NB), dim3(1024), 0, stream,
                     out + OFF_COMB, out + OFF_IDX, selIdx);
  hipLaunchKernelGGL(gather_kernel, dim3(NB*KSEL/2), dim3(256), 0, stream,
                     feat, selIdx, out);
  hipLaunchKernelGGL(top16_kernel, dim3(NB*CC), dim3(256), 0, stream,
                     a_logits, mz, top16);
  hipLaunchKernelGGL(mlp_kernel, dim3(NB*CC*16), dim3(256), 0, stream,
                     feat, W1, b1, W2, b2, top16, cews);
  hipLaunchKernelGGL(loss_kernel, dim3(1), dim3(64), 0, stream,
                     cews, out + OFF_LOSS);
}

// Round 8
// 251.809 us; speedup vs baseline: 1.5104x; 1.0209x over previous
//
#include <hip/hip_runtime.h>

#define NB 4
#define NP 16384
#define DD 512
#define HH 256
#define CC 2
#define KSEL 11468
#define TOTP (NB*NP)
#define BCAP 4096

// d_out offsets (floats)
#define OFF_COMB (NB*KSEL*DD)            // 23486464
#define OFF_IDX  (OFF_COMB + NB*NP)      // 23552000
#define OFF_LOSS (OFF_IDX + NB*KSEL)     // 23597872

// ws offsets (floats)
#define WS_ALOGIT 0
#define WS_SELIDX (2*NB*CC*NP)               // 262144 (ints)
#define WS_MZ     (WS_SELIDX + NB*KSEL)      // (16 floats)
#define WS_BCNT   (WS_MZ + 16)               // ints (4)
#define WS_BLIST  (WS_BCNT + 4)              // ints (4*BCAP)
#define WS_TOP16  (WS_BLIST + NB*BCAP)       // ints (8*16)
#define WS_CE     (WS_TOP16 + 128)           // floats (128)
#define WS_CNT    (WS_CE + 128)              // 1 uint (mlp/loss done-counter)

typedef __attribute__((ext_vector_type(8))) short short8x;
typedef __attribute__((ext_vector_type(4))) float f32x4;

__device__ __forceinline__ unsigned short f2bf(float x){
  unsigned u = __float_as_uint(x);
  unsigned r = (u + 0x7FFFu + ((u >> 16) & 1u)) >> 16;
  return (unsigned short)r;
}

// HW packed f32->bf16 (RNE, same rounding as f2bf): lo -> bits[15:0], hi -> bits[31:16]
__device__ __forceinline__ unsigned cvtpk(float lo, float hi){
  unsigned r;
  asm("v_cvt_pk_bf16_f32 %0, %1, %2" : "=v"(r) : "v"(lo), "v"(hi));
  return r;
}

// ---------------------------------------------------------------------------
// Wa (512x256 f32) -> Wa_t (256x512 bf16), transposed, stored at d_out head.
// Also zeroes the mlp/loss done-counter for this call (graph-replay safe).
// ---------------------------------------------------------------------------
__global__ __launch_bounds__(256) void waconv_kernel(
    const float* __restrict__ Wa, unsigned short* __restrict__ WaT,
    unsigned* __restrict__ donecnt)
{
  __shared__ float tile[32][33];
  const int tx = threadIdx.x, ty = threadIdx.y;   // 32 x 8
  const int k0 = blockIdx.x * 32, n0 = blockIdx.y * 32;
  if (blockIdx.x==0 && blockIdx.y==0 && tx==0 && ty==0) donecnt[0] = 0u;
  #pragma unroll
  for (int i=0;i<4;++i)
    tile[ty+8*i][tx] = Wa[(size_t)(k0+ty+8*i)*HH + n0 + tx];
  __syncthreads();
  #pragma unroll
  for (int i=0;i<4;++i)
    WaT[(size_t)(n0+ty+8*i)*DD + k0 + tx] = f2bf(tile[tx][ty+8*i]);
}

// ---------------------------------------------------------------------------
// MFMA GEMM: a_logits[b,c,n] = Wbr[c].relu(f[n]@Wa+ba) + bbr[c], bf16 inputs.
// BM=128, BN=256(full H), BK=64; 8 waves (2M x 4N), wave tile 64x64.
// r8: A-staging via v_cvt_pk_bf16_f32 (4x fewer VALU ops than bit-twiddle);
// register epilogue (per-lane nf-partials + fr-shuffle + 4KB exchange) replaces
// the 128KB LDS h-tile round trip (2 phases, 4 barriers -> 1 barrier).
// ---------------------------------------------------------------------------
__global__ __launch_bounds__(512) void gemm_mfma_kernel(
    const float* __restrict__ feat, const unsigned short* __restrict__ WaT,
    const float* __restrict__ ba, const float* __restrict__ Wbr,
    const float* __restrict__ bbr, float* __restrict__ aL)
{
  __shared__ __attribute__((aligned(16))) unsigned char smem[49152];
  __shared__ float sBA[HH], sW0[HH], sW1[HH];
  unsigned char* sA = smem;                 // 128*64 bf16 = 16 KB (swizzled)
  unsigned char* sB = smem + 16384;         // 256*64 bf16 = 32 KB (swizzled)

  const int tid  = threadIdx.x;
  const int lane = tid & 63;
  const int wid  = tid >> 6;
  const int wm = wid >> 2, wn = wid & 3;
  const int fr = lane & 15, fq = lane >> 4;
  const int p0 = blockIdx.x * 128;
  const float bb0 = bbr[0], bb1 = bbr[1];

  if (tid < HH){ sBA[tid] = ba[tid]; sW0[tid] = Wbr[tid]; sW1[tid] = Wbr[HH+tid]; }

  f32x4 acc[4][4];
  #pragma unroll
  for (int i=0;i<4;++i)
    #pragma unroll
    for (int j=0;j<4;++j)
      acc[i][j] = (f32x4){0.f,0.f,0.f,0.f};

  const int am = tid >> 2, akq = (tid & 3) * 16;     // A staging: row, k-offset
  const int bn = tid >> 1, bhf = tid & 1;            // B staging

  for (int k0 = 0; k0 < DD; k0 += 64){
    __syncthreads();
    // ---- stage A: 128x64 fp32 -> bf16 via cvt_pk, swizzled K-major
    {
      const float4* src = reinterpret_cast<const float4*>(
          feat + (size_t)(p0 + am)*DD + k0 + akq);
      float4 v0 = src[0], v1 = src[1], v2 = src[2], v3 = src[3];
      uint4 w0, w1;
      w0.x = cvtpk(v0.x, v0.y); w0.y = cvtpk(v0.z, v0.w);
      w0.z = cvtpk(v1.x, v1.y); w0.w = cvtpk(v1.z, v1.w);
      w1.x = cvtpk(v2.x, v2.y); w1.y = cvtpk(v2.z, v2.w);
      w1.z = cvtpk(v3.x, v3.y); w1.w = cvtpk(v3.z, v3.w);
      const int swz = (am & 7) << 4;
      *reinterpret_cast<uint4*>(sA + (((am*128) + akq*2) ^ swz)) = w0;
      *reinterpret_cast<uint4*>(sA + (((am*128) + akq*2 + 16) ^ swz)) = w1;
    }
    // ---- stage B: 256x64 bf16 from WaT, swizzled K-major
    {
      const uint4* src = reinterpret_cast<const uint4*>(
          WaT + (size_t)bn*DD + k0 + bhf*32);
      uint4 q0 = src[0], q1 = src[1], q2 = src[2], q3 = src[3];
      const int swz = (bn & 7) << 4;
      const int base = bn*128 + bhf*64;
      *reinterpret_cast<uint4*>(sB + ((base     ) ^ swz)) = q0;
      *reinterpret_cast<uint4*>(sB + ((base + 16) ^ swz)) = q1;
      *reinterpret_cast<uint4*>(sB + ((base + 32) ^ swz)) = q2;
      *reinterpret_cast<uint4*>(sB + ((base + 48) ^ swz)) = q3;
    }
    __syncthreads();
    // ---- MFMA
    #pragma unroll
    for (int kf = 0; kf < 2; ++kf){
      short8x af[4], bf[4];
      #pragma unroll
      for (int mf = 0; mf < 4; ++mf){
        int m_loc = wm*64 + mf*16 + fr;
        int off = ((m_loc*128 + kf*64 + fq*16) ^ ((m_loc & 7) << 4));
        af[mf] = *reinterpret_cast<const short8x*>(sA + off);
      }
      #pragma unroll
      for (int nf = 0; nf < 4; ++nf){
        int n_loc = wn*64 + nf*16 + fr;
        int off = ((n_loc*128 + kf*64 + fq*16) ^ ((n_loc & 7) << 4));
        bf[nf] = *reinterpret_cast<const short8x*>(sB + off);
      }
      #pragma unroll
      for (int mf = 0; mf < 4; ++mf)
        #pragma unroll
        for (int nf = 0; nf < 4; ++nf)
          acc[mf][nf] = __builtin_amdgcn_mfma_f32_16x16x32_bf16(
              af[mf], bf[nf], acc[mf][nf], 0, 0, 0);
    }
  }
  __syncthreads();

  // ---- register epilogue: x = relu(acc + ba[col]); project onto Wbr rows.
  // Per-lane partial over nf, butterfly over the 16 fr-lanes, 4KB exchange
  // over the 4 wn-waves, fixed-order final sum.
  float* ex = reinterpret_cast<float*>(smem);      // [128 rows][4 wn][2 c]
  #pragma unroll
  for (int mf = 0; mf < 4; ++mf){
    #pragma unroll
    for (int r = 0; r < 4; ++r){
      float s0 = 0.f, s1 = 0.f;
      #pragma unroll
      for (int nf = 0; nf < 4; ++nf){
        int col = wn*64 + nf*16 + fr;
        float x = fmaxf(acc[mf][nf][r] + sBA[col], 0.f);
        s0 += x * sW0[col];
        s1 += x * sW1[col];
      }
      s0 += __shfl_xor(s0,1); s1 += __shfl_xor(s1,1);
      s0 += __shfl_xor(s0,2); s1 += __shfl_xor(s1,2);
      s0 += __shfl_xor(s0,4); s1 += __shfl_xor(s1,4);
      s0 += __shfl_xor(s0,8); s1 += __shfl_xor(s1,8);
      if (fr == 0){
        int row = wm*64 + mf*16 + fq*4 + r;       // 0..127
        ex[(row*4 + wn)*2 + 0] = s0;
        ex[(row*4 + wn)*2 + 1] = s1;
      }
    }
  }
  __syncthreads();
  if (tid < 256){
    const int row = tid >> 1, c = tid & 1;
    float s = ((ex[(row*4+0)*2+c] + ex[(row*4+1)*2+c]) +
               (ex[(row*4+2)*2+c] + ex[(row*4+3)*2+c]));
    int p = p0 + row;
    int b = p >> 14, nl = p & (NP-1);
    aL[((size_t)b*CC + c)*NP + nl] = s + (c ? bb1 : bb0);
  }
}

// ---------------------------------------------------------------------------
// Per-(b,c) row max + 1/Z (double accum). One block per row (8 blocks).
// (unchanged — proven)
// ---------------------------------------------------------------------------
__global__ __launch_bounds__(1024) void smstat_kernel(
    const float* __restrict__ aL, float* __restrict__ mz)
{
  __shared__ float  s_redf[16];
  __shared__ double s_redd[16];
  __shared__ float  s_max;
  const int tid = threadIdx.x;
  const int lane = tid & 63, wid = tid >> 6;
  const int r = blockIdx.x;                 // r = b*2 + c
  const float* a = aL + (size_t)r*NP;
  float m = -1e30f;
  for (int n=tid; n<NP; n+=1024) m = fmaxf(m, a[n]);
  #pragma unroll
  for (int off=1; off<64; off<<=1) m = fmaxf(m, __shfl_xor(m, off));
  if (lane==0) s_redf[wid]=m;
  __syncthreads();
  if (tid==0){ float mm=s_redf[0]; for(int w=1;w<16;++w) mm=fmaxf(mm,s_redf[w]); s_max=mm; }
  __syncthreads();
  m = s_max;
  double ls = 0.0;
  for (int n=tid;n<NP;n+=1024) ls += (double)expf(a[n]-m);
  #pragma unroll
  for (int off=1; off<64; off<<=1) ls += __shfl_xor(ls, off);
  if (lane==0) s_redd[wid]=ls;
  __syncthreads();
  if (tid==0){
    double t=0; for(int w=0;w<16;++w) t+=s_redd[w];
    mz[r*2+0]=m; mz[r*2+1]=(float)(1.0/t);
  }
}

// ---------------------------------------------------------------------------
// Fused: combined finalize + approx threshold radix (2 bits/round, 10 rounds)
// + band list. Register-resident chunks.
// ---------------------------------------------------------------------------
__global__ __launch_bounds__(1024) void selTF_kernel(
    const float* __restrict__ aL, const float* __restrict__ mz,
    float* __restrict__ comb, int* __restrict__ bcnt, int* __restrict__ blist)
{
  __shared__ unsigned s_red[2][16][3];
  __shared__ int s_cnt;
  const int tid = threadIdx.x;
  const int b = blockIdx.x;
  const int lane = tid & 63, wid = tid >> 6;
  const float m0 = mz[b*4+0], iz0 = mz[b*4+1], m1 = mz[b*4+2], iz1 = mz[b*4+3];
  const float* a0 = aL + ((size_t)b*CC + 0)*NP;
  const float* a1 = aL + ((size_t)b*CC + 1)*NP;
  float* oc = comb + (size_t)b*NP;
  const int n0 = tid*16;

  unsigned v[16];
  #pragma unroll
  for (int g=0; g<4; ++g){
    float4 qa = *reinterpret_cast<const float4*>(a0 + n0 + g*4);
    float4 qb = *reinterpret_cast<const float4*>(a1 + n0 + g*4);
    float4 CV;
    CV.x = 0.5f*(expf(qa.x-m0)*iz0 + expf(qb.x-m1)*iz1);
    CV.y = 0.5f*(expf(qa.y-m0)*iz0 + expf(qb.y-m1)*iz1);
    CV.z = 0.5f*(expf(qa.z-m0)*iz0 + expf(qb.z-m1)*iz1);
    CV.w = 0.5f*(expf(qa.w-m0)*iz0 + expf(qb.w-m1)*iz1);
    *reinterpret_cast<float4*>(oc + n0 + g*4) = CV;
    v[g*4+0]=__float_as_uint(CV.x);
    v[g*4+1]=__float_as_uint(CV.y);
    v[g*4+2]=__float_as_uint(CV.z);
    v[g*4+3]=__float_as_uint(CV.w);
  }
  if (tid==0) s_cnt = 0;

  unsigned cur = 0;
  #pragma unroll 1
  for (int bit=30; bit>=12; bit-=2){
    const unsigned t1 = cur | (1u<<bit), t2 = cur | (2u<<bit), t3 = cur | (3u<<bit);
    int c1=0,c2=0,c3=0;
    #pragma unroll
    for (int i=0;i<16;++i){
      c1 += (v[i] >= t1) ? 1 : 0;
      c2 += (v[i] >= t2) ? 1 : 0;
      c3 += (v[i] >= t3) ? 1 : 0;
    }
    #pragma unroll
    for (int off=1; off<64; off<<=1){
      c1+=__shfl_xor(c1,off); c2+=__shfl_xor(c2,off); c3+=__shfl_xor(c3,off);
    }
    const int pb = (bit>>1)&1;
    if (lane==0){ s_red[pb][wid][0]=(unsigned)c1; s_red[pb][wid][1]=(unsigned)c2; s_red[pb][wid][2]=(unsigned)c3; }
    __syncthreads();
    unsigned T1=0,T2=0,T3=0;
    #pragma unroll
    for (int w=0;w<16;++w){ T1+=s_red[pb][w][0]; T2+=s_red[pb][w][1]; T3+=s_red[pb][w][2]; }
    if      (T3 >= KSEL) cur = t3;
    else if (T2 >= KSEL) cur = t2;
    else if (T1 >= KSEL) cur = t1;
  }
  const float Tv = __uint_as_float(cur);
  const float lo = Tv*0.989f, hi = Tv*1.0115f;
  #pragma unroll
  for (int i=0;i<16;++i){
    float x = __uint_as_float(v[i]);
    if (x >= lo && x <= hi){
      int s = atomicAdd(&s_cnt, 1);
      if (s < BCAP) blist[b*BCAP + s] = n0 + i;
    }
  }
  __syncthreads();
  if (tid==0) bcnt[b] = (s_cnt < BCAP) ? s_cnt : BCAP;
}

// ---------------------------------------------------------------------------
// Exact fp32 recompute of combined for band members — 16 candidates/block,
// GEMM-tiled (Wa staged through LDS once per block). (unchanged — proven r7)
// ---------------------------------------------------------------------------
__global__ __launch_bounds__(512) void recomp_kernel(
    const float* __restrict__ feat, const float* __restrict__ Wa,
    const float* __restrict__ ba, const float* __restrict__ Wbr,
    const float* __restrict__ bbr, const float* __restrict__ mz,
    const int* __restrict__ bcnt, const int* __restrict__ blist,
    float* __restrict__ comb)
{
  __shared__ float fS[16][DD];       // 32 KB: 16 candidate rows
  __shared__ float waS[32][HH];      // 32 KB: one Wa k-tile
  __shared__ int   s_n[16];
  const int tid = threadIdx.x;
  const int b  = blockIdx.x >> 8;            // 256 chunks per batch
  const int g0 = (blockIdx.x & 255) * 16;    // first candidate slot
  const int cnt = bcnt[b];
  if (g0 >= cnt) return;                     // whole chunk inactive
  if (tid < 16)
    s_n[tid] = (g0 + tid < cnt) ? blist[b*BCAP + g0 + tid] : -1;
  __syncthreads();
  #pragma unroll
  for (int pass=0; pass<4; ++pass){
    const int j = pass*4 + (tid>>7);
    const int c4 = (tid & 127)*4;
    const int n = s_n[j];
    if (n >= 0){
      float4 v = *reinterpret_cast<const float4*>(feat + ((size_t)b*NP + n)*DD + c4);
      *reinterpret_cast<float4*>(&fS[j][c4]) = v;
    }
  }

  const int grp = tid >> 5, l32 = tid & 31;
  const int h0 = l32*4;
  float acc[8];
  #pragma unroll
  for (int i=0;i<8;++i) acc[i]=0.f;

  #pragma unroll 1
  for (int kt=0; kt<16; ++kt){
    __syncthreads();
    {
      const float4* src = reinterpret_cast<const float4*>(Wa + (size_t)(kt*32)*HH);
      float4* dst = reinterpret_cast<float4*>(&waS[0][0]);
      #pragma unroll
      for (int q=0; q<4; ++q) dst[tid + 512*q] = src[tid + 512*q];
    }
    __syncthreads();
    if (s_n[grp] >= 0){
      #pragma unroll
      for (int kk4=0; kk4<8; ++kk4){
        const float4 fv = *reinterpret_cast<const float4*>(&fS[grp][kt*32 + kk4*4]);
        const float fx[4] = {fv.x, fv.y, fv.z, fv.w};
        #pragma unroll
        for (int u=0; u<4; ++u){
          const int kk = kk4*4 + u;
          float4 w0 = *reinterpret_cast<const float4*>(&waS[kk][h0]);
          float4 w1 = *reinterpret_cast<const float4*>(&waS[kk][128 + h0]);
          acc[0] += fx[u]*w0.x; acc[1] += fx[u]*w0.y;
          acc[2] += fx[u]*w0.z; acc[3] += fx[u]*w0.w;
          acc[4] += fx[u]*w1.x; acc[5] += fx[u]*w1.y;
          acc[6] += fx[u]*w1.z; acc[7] += fx[u]*w1.w;
        }
      }
    }
  }
  if (s_n[grp] < 0) return;
  float p0 = 0.f, p1 = 0.f;
  #pragma unroll
  for (int i=0;i<8;++i){
    const int h = (i<4) ? (h0+i) : (128 + h0 + (i-4));
    float x = fmaxf(acc[i] + ba[h], 0.f);
    p0 += x * Wbr[h];
    p1 += x * Wbr[HH+h];
  }
  #pragma unroll
  for (int off=1; off<32; off<<=1){ p0+=__shfl_xor(p0,off); p1+=__shfl_xor(p1,off); }
  if (l32==0){
    const float m0 = mz[b*4+0], iz0 = mz[b*4+1], m1 = mz[b*4+2], iz1 = mz[b*4+3];
    float l0 = p0 + bbr[0];
    float l1 = p1 + bbr[1];
    comb[(size_t)b*NP + s_n[grp]] = 0.5f*(expf(l0-m0)*iz0 + expf(l1-m1)*iz1);
  }
}

// ---------------------------------------------------------------------------
// Exact top-k selection on refined combined. 2-bit radix (16 rounds) +
// register-resident chunks; emission ownership unchanged (byte-identical out).
// ---------------------------------------------------------------------------
__global__ __launch_bounds__(1024) void select_kernel(
    const float* __restrict__ comb, float* __restrict__ outIdxF,
    int* __restrict__ selIdx)
{
  __shared__ unsigned s_red[2][16][3];
  __shared__ unsigned s_wsum[16];
  const int tid = threadIdx.x;
  const int b = blockIdx.x;
  const int lane = tid & 63, wid = tid >> 6;
  const float* row = comb + (size_t)b*NP;

  unsigned v[16];
  {
    const float4* rp = reinterpret_cast<const float4*>(row + tid*16);
    #pragma unroll
    for (int g=0; g<4; ++g){
      float4 q = rp[g];
      v[g*4+0]=__float_as_uint(q.x);
      v[g*4+1]=__float_as_uint(q.y);
      v[g*4+2]=__float_as_uint(q.z);
      v[g*4+3]=__float_as_uint(q.w);
    }
  }
  // ---- radix threshold: 2 bits per round, 16 rounds, 1 barrier each
  unsigned cur = 0;
  #pragma unroll 1
  for (int bit=30; bit>=0; bit-=2){
    const unsigned t1 = cur | (1u<<bit), t2 = cur | (2u<<bit), t3 = cur | (3u<<bit);
    int c1=0,c2=0,c3=0;
    #pragma unroll
    for (int i=0;i<16;++i){
      c1 += (v[i] >= t1) ? 1 : 0;
      c2 += (v[i] >= t2) ? 1 : 0;
      c3 += (v[i] >= t3) ? 1 : 0;
    }
    #pragma unroll
    for (int off=1; off<64; off<<=1){
      c1+=__shfl_xor(c1,off); c2+=__shfl_xor(c2,off); c3+=__shfl_xor(c3,off);
    }
    const int pb = (bit>>1)&1;
    if (lane==0){ s_red[pb][wid][0]=(unsigned)c1; s_red[pb][wid][1]=(unsigned)c2; s_red[pb][wid][2]=(unsigned)c3; }
    __syncthreads();
    unsigned T1=0,T2=0,T3=0;
    #pragma unroll
    for (int w=0;w<16;++w){ T1+=s_red[pb][w][0]; T2+=s_red[pb][w][1]; T3+=s_red[pb][w][2]; }
    if      (T3 >= KSEL) cur = t3;
    else if (T2 >= KSEL) cur = t2;
    else if (T1 >= KSEL) cur = t1;
  }
  const unsigned T = cur;
  // ---- strictly-greater count
  {
    int c = 0;
    #pragma unroll
    for (int i=0;i<16;++i) c += (v[i] > T) ? 1 : 0;
    #pragma unroll
    for (int off=1; off<64; off<<=1) c += __shfl_xor(c, off);
    if (lane==0) s_red[1][wid][0] = (unsigned)c;
  }
  __syncthreads();
  unsigned gtot=0;
  #pragma unroll
  for (int w=0;w<16;++w) gtot += s_red[1][w][0];
  const int extra = KSEL - (int)gtot;

  // ---- exclusive prefix of equality counts
  int eqc=0;
  #pragma unroll
  for (int i=0;i<16;++i) eqc += (v[i]==T) ? 1 : 0;
  unsigned inc = (unsigned)eqc;
  #pragma unroll
  for (int off=1; off<64; off<<=1){
    unsigned o = __shfl_up(inc, off);
    if (lane >= off) inc += o;
  }
  if (lane==63) s_wsum[wid] = inc;
  __syncthreads();
  unsigned wbase = 0;
  for (int w=0; w<wid; ++w) wbase += s_wsum[w];
  const int eqBase = (int)(wbase + inc) - eqc;

  // ---- selected-count prefix
  int eq=eqBase, sc=0;
  #pragma unroll
  for (int i=0;i<16;++i){
    unsigned x = v[i];
    if (x==T){ if (eq<extra) sc++; eq++; }
    else if (x>T) sc++;
  }
  unsigned inc2 = (unsigned)sc;
  #pragma unroll
  for (int off=1; off<64; off<<=1){
    unsigned o = __shfl_up(inc2, off);
    if (lane >= off) inc2 += o;
  }
  __syncthreads();
  if (lane==63) s_wsum[wid] = inc2;
  __syncthreads();
  unsigned wbase2 = 0;
  for (int w=0; w<wid; ++w) wbase2 += s_wsum[w];
  int pos = (int)(wbase2 + inc2) - sc;

  // ---- emit
  eq=eqBase;
  #pragma unroll
  for (int i=0;i<16;++i){
    unsigned x = v[i];
    int f=0;
    if (x==T){ if (eq<extra) f=1; eq++; }
    else if (x>T) f=1;
    if (f){
      int n = tid*16 + i;
      outIdxF[(size_t)b*KSEL + pos] = (float)n;
      selIdx[(size_t)b*KSEL + pos] = n;
      pos++;
    }
  }
}

// ---------------------------------------------------------------------------
// Gather selected rows. (unchanged — proven)
// ---------------------------------------------------------------------------
__global__ __launch_bounds__(256) void gather_kernel(
    const float* __restrict__ feat, const int* __restrict__ selIdx,
    float* __restrict__ outSel)
{
  const int tid = threadIdx.x;
  const int row = blockIdx.x*2 + (tid>>7);
  const int c4 = tid & 127;
  const int b = row / KSEL;
  const int idx = selIdx[row];
  const float4 v = *reinterpret_cast<const float4*>(feat + ((size_t)b*NP + idx)*DD + c4*4);
  *reinterpret_cast<float4*>(outSel + (size_t)row*DD + c4*4) = v;
}

// ---------------------------------------------------------------------------
// Per-(b,c) top-8/bottom-8 on attn computed on the fly from aL + mz.
// (unchanged — proven)
// ---------------------------------------------------------------------------
__global__ __launch_bounds__(256) void top16_kernel(
    const float* __restrict__ aL, const float* __restrict__ mz,
    int* __restrict__ top16)
{
  __shared__ unsigned long long wkT[4][8];
  __shared__ unsigned long long wkB[4][8];
  const int tid = threadIdx.x;
  const int bid = blockIdx.x;                // r = b*2 + c
  const int lane = tid & 63, wid = tid >> 6;
  const float* a = aL + (size_t)bid*NP;
  const float m = mz[bid*2+0], iz = mz[bid*2+1];

  unsigned long long t8[8], b8[8];
  #pragma unroll
  for (int i=0;i<8;++i){ t8[i]=0ull; b8[i]=~0ull; }

  for (int j=0;j<16;++j){
    const int n4 = tid + 256*j;
    const float4 v = *reinterpret_cast<const float4*>(a + 4*n4);
    float xs[4];
    xs[0] = expf(v.x-m)*iz; xs[1] = expf(v.y-m)*iz;
    xs[2] = expf(v.z-m)*iz; xs[3] = expf(v.w-m)*iz;
    #pragma unroll
    for (int q=0;q<4;++q){
      const int n = 4*n4 + q;
      const unsigned vb = __float_as_uint(xs[q]);
      unsigned long long kt = ((unsigned long long)vb<<32) | (unsigned)(NP-1-n);
      if (kt > t8[7]){
        t8[7]=kt;
        #pragma unroll
        for (int i=7;i>0;--i){ if (t8[i]>t8[i-1]){ unsigned long long t=t8[i-1]; t8[i-1]=t8[i]; t8[i]=t; } }
      }
      unsigned long long kb = ((unsigned long long)vb<<32) | (unsigned)n;
      if (kb < b8[7]){
        b8[7]=kb;
        #pragma unroll
        for (int i=7;i>0;--i){ if (b8[i]<b8[i-1]){ unsigned long long t=b8[i-1]; b8[i-1]=b8[i]; b8[i]=t; } }
      }
    }
  }

  #pragma unroll
  for (int pick=0; pick<8; ++pick){
    unsigned long long loc = t8[0];
    #pragma unroll
    for (int i=1;i<8;++i) loc = t8[i]>loc ? t8[i] : loc;
    #pragma unroll
    for (int off=1; off<64; off<<=1){ unsigned long long o=__shfl_xor(loc,off); loc=o>loc?o:loc; }
    if (lane==0) wkT[wid][pick]=loc;
    #pragma unroll
    for (int i=0;i<8;++i) if (t8[i]==loc) t8[i]=0ull;
  }
  #pragma unroll
  for (int pick=0; pick<8; ++pick){
    unsigned long long loc = b8[0];
    #pragma unroll
    for (int i=1;i<8;++i) loc = b8[i]<loc ? b8[i] : loc;
    #pragma unroll
    for (int off=1; off<64; off<<=1){ unsigned long long o=__shfl_xor(loc,off); loc=o<loc?o:loc; }
    if (lane==0) wkB[wid][pick]=loc;
    #pragma unroll
    for (int i=0;i<8;++i) if (b8[i]==loc) b8[i]=~0ull;
  }
  __syncthreads();

  if (wid==0){
    unsigned long long k = (lane<32) ? wkT[lane>>3][lane&7] : 0ull;
    #pragma unroll
    for (int pick=0; pick<8; ++pick){
      unsigned long long loc = k;
      #pragma unroll
      for (int off=1; off<64; off<<=1){ unsigned long long o=__shfl_xor(loc,off); loc=o>loc?o:loc; }
      if (k==loc) k=0ull;
      if (lane==0) top16[bid*16+pick] = NP-1-(int)(loc & 0xFFFFFFFFull);
    }
    unsigned long long kb = (lane<32) ? wkB[lane>>3][lane&7] : ~0ull;
    #pragma unroll
    for (int pick=0; pick<8; ++pick){
      unsigned long long loc = kb;
      #pragma unroll
      for (int off=1; off<64; off<<=1){ unsigned long long o=__shfl_xor(loc,off); loc=o<loc?o:loc; }
      if (kb==loc) kb=~0ull;
      if (lane==0) top16[bid*16+8+pick] = (int)(loc & 0xFFFFFFFFull);
    }
  }
}

// ---------------------------------------------------------------------------
// Instance MLP + CE partial, one block per (b,c,r); the 128th block to finish
// sums all partials in fixed index order (deterministic) and writes the loss.
// ---------------------------------------------------------------------------
__global__ __launch_bounds__(256) void mlp_kernel(
    const float* __restrict__ feat, const float* __restrict__ W1,
    const float* __restrict__ b1, const float* __restrict__ W2,
    const float* __restrict__ b2, const int* __restrict__ top16,
    float* __restrict__ cews, unsigned* __restrict__ donecnt,
    float* __restrict__ out_loss)
{
  __shared__ float fS[DD];
  __shared__ float r0[4], r1[4];
  const int tid = threadIdx.x;
  const int bid = blockIdx.x;
  const int r = bid & 15, c = (bid >> 4) & 1, b = bid >> 5;
  const int lane = tid & 63, wid = tid >> 6;
  const int gi = top16[(b*2+c)*16 + r];
  if (tid < 128){
    float4 v = *reinterpret_cast<const float4*>(feat + ((size_t)b*NP + gi)*DD + tid*4);
    *reinterpret_cast<float4*>(&fS[tid*4]) = v;
  }
  __syncthreads();
  const float* w1c = W1 + (size_t)c*DD*HH;
  float a0=0.f,a1=0.f,a2=0.f,a3=0.f;
  #pragma unroll 4
  for (int d=0; d<DD; d+=4){
    a0 += fS[d+0]*w1c[(size_t)(d+0)*HH + tid];
    a1 += fS[d+1]*w1c[(size_t)(d+1)*HH + tid];
    a2 += fS[d+2]*w1c[(size_t)(d+2)*HH + tid];
    a3 += fS[d+3]*w1c[(size_t)(d+3)*HH + tid];
  }
  float h = fmaxf((a0+a1)+(a2+a3) + b1[c*HH+tid], 0.f);
  float p0 = h*W2[(size_t)(c*HH+tid)*2 + 0];
  float p1 = h*W2[(size_t)(c*HH+tid)*2 + 1];
  #pragma unroll
  for (int off=1; off<64; off<<=1){ p0+=__shfl_xor(p0,off); p1+=__shfl_xor(p1,off); }
  if (lane==0){ r0[wid]=p0; r1[wid]=p1; }
  __syncthreads();
  if (tid==0){
    float l0 = (r0[0]+r0[1])+(r0[2]+r0[3]) + b2[c*2+0];
    float l1 = (r1[0]+r1[1])+(r1[2]+r1[3]) + b2[c*2+1];
    float mm = fmaxf(l0,l1);
    float lse = mm + logf(expf(l0-mm)+expf(l1-mm));
    float chosen = (r<8) ? l1 : l0;
    cews[bid] = lse - chosen;
    __threadfence();
    unsigned old = atomicAdd(donecnt, 1u);
    if (old == 127u){
      __threadfence();
      float s=0.f;
      for (int i=0;i<128;++i) s += cews[i];
      out_loss[0] = s / 128.0f;
    }
  }
}

extern "C" void kernel_launch(void* const* d_in, const int* in_sizes, int n_in,
                              void* d_out, int out_size, void* d_ws, size_t ws_size,
                              hipStream_t stream) {
  const float* feat = (const float*)d_in[0];
  const float* Wa   = (const float*)d_in[1];
  const float* ba   = (const float*)d_in[2];
  const float* Wbr  = (const float*)d_in[3];
  const float* bbr  = (const float*)d_in[4];
  const float* W1   = (const float*)d_in[5];
  const float* b1   = (const float*)d_in[6];
  const float* W2   = (const float*)d_in[7];
  const float* b2   = (const float*)d_in[8];
  float* out = (float*)d_out;
  float* ws  = (float*)d_ws;

  float* a_logits = ws + WS_ALOGIT;
  int*   selIdx   = (int*)(ws + WS_SELIDX);
  float* mz       = ws + WS_MZ;
  int*   bcnt     = (int*)(ws + WS_BCNT);
  int*   blist    = (int*)(ws + WS_BLIST);
  int*   top16    = (int*)(ws + WS_TOP16);
  float* cews     = ws + WS_CE;
  unsigned* donecnt = (unsigned*)(ws + WS_CNT);

  unsigned short* WaT = (unsigned short*)d_out;   // head of selected region;
                                                  // fully overwritten by gather

  hipLaunchKernelGGL(waconv_kernel, dim3(DD/32, HH/32), dim3(32,8), 0, stream,
                     Wa, WaT, donecnt);
  hipLaunchKernelGGL(gemm_mfma_kernel, dim3(TOTP/128), dim3(512), 0, stream,
                     feat, WaT, ba, Wbr, bbr, a_logits);
  hipLaunchKernelGGL(smstat_kernel, dim3(NB*CC), dim3(1024), 0, stream,
                     a_logits, mz);
  hipLaunchKernelGGL(selTF_kernel, dim3(NB), dim3(1024), 0, stream,
                     a_logits, mz, out + OFF_COMB, bcnt, blist);
  hipLaunchKernelGGL(recomp_kernel, dim3(NB*256), dim3(512), 0, stream,
                     feat, Wa, ba, Wbr, bbr, mz, bcnt, blist, out + OFF_COMB);
  hipLaunchKernelGGL(select_kernel, dim3(NB), dim3(1024), 0, stream,
                     out + OFF_COMB, out + OFF_IDX, selIdx);
  hipLaunchKernelGGL(gather_kernel, dim3(NB*KSEL/2), dim3(256), 0, stream,
                     feat, selIdx, out);
  hipLaunchKernelGGL(top16_kernel, dim3(NB*CC), dim3(256), 0, stream,
                     a_logits, mz, top16);
  hipLaunchKernelGGL(mlp_kernel, dim3(NB*CC*16), dim3(256), 0, stream,
                     feat, W1, b1, W2, b2, top16, cews, donecnt, out + OFF_LOSS);
}